// Round 3
// baseline (198.038 us; speedup 1.0000x reference)
//
#include <hip/hip_runtime.h>

typedef unsigned short u16;
typedef __bf16 bf16x8 __attribute__((ext_vector_type(8)));
typedef float f32x4 __attribute__((ext_vector_type(4)));

#define MFMA16(a, b, c) __builtin_amdgcn_mfma_f32_16x16x32_bf16((a), (b), (c), 0, 0, 0)

// Problem constants
#define Bn 4
#define Cn 256
#define Ln 2048
#define Hn 8
#define Dn 64
#define HID 512

__device__ __forceinline__ u16 bf16_rne(float f) {
  unsigned u = __builtin_bit_cast(unsigned, f);
  u += 0x7FFFu + ((u >> 16) & 1u);
  return (u16)(u >> 16);
}

__device__ __forceinline__ unsigned pack2(float a, float b) {
  return (unsigned)bf16_rne(a) | ((unsigned)bf16_rne(b) << 16);
}

__device__ __forceinline__ float fast_exp2(float x) {
#if __has_builtin(__builtin_amdgcn_exp2f)
  return __builtin_amdgcn_exp2f(x);
#else
  return exp2f(x);
#endif
}

__device__ __forceinline__ float fast_rcp(float x) {
#if __has_builtin(__builtin_amdgcn_rcpf)
  return __builtin_amdgcn_rcpf(x);
#else
  return 1.0f / x;
#endif
}

// async 16B global -> LDS DMA. HW dest = wave-uniform base + lane*16.
__device__ __forceinline__ void async_load16(const u16* g, u16* l) {
  __builtin_amdgcn_global_load_lds(
      (const __attribute__((address_space(1))) void*)g,
      (__attribute__((address_space(3))) void*)l, 16, 0, 0);
}

// ---------------- prep: weights -> bf16 (q rows pre-scaled by 0.125*log2e) ---
__global__ __launch_bounds__(256) void prep_weights(const float* __restrict__ wqkv,
                                                    const float* __restrict__ wout,
                                                    u16* __restrict__ wq,
                                                    u16* __restrict__ wo) {
  int i = blockIdx.x * 256 + threadIdx.x;
  const float QSCALE = 0.125f * 1.44269504088896340736f;  // scale * log2(e)
  if (i < 3 * HID * Cn) {
    float v = wqkv[i];
    if (i < HID * Cn) v *= QSCALE;  // q rows
    wq[i] = bf16_rne(v);
  } else {
    int j = i - 3 * HID * Cn;
    wo[j] = bf16_rne(wout[j]);
  }
}

// ---------------- prep: x [b][256][2048] fp32 -> xT [b][2048][256] bf16 ------
__global__ __launch_bounds__(256) void transpose_x(const float* __restrict__ x,
                                                   u16* __restrict__ xT) {
  __shared__ u16 tile[64][72];
  const int b = blockIdx.z, ct = blockIdx.y, lt = blockIdx.x;
  const int t = threadIdx.x;
  const float* xp = x + ((size_t)b * Cn + ct * 64) * Ln + lt * 64;
  for (int pass = 0; pass < 4; ++pass) {
    int c = pass * 16 + (t >> 4);
    int l4 = (t & 15) * 4;
    float4 v = *(const float4*)(xp + (size_t)c * Ln + l4);
    tile[l4 + 0][c] = bf16_rne(v.x);
    tile[l4 + 1][c] = bf16_rne(v.y);
    tile[l4 + 2][c] = bf16_rne(v.z);
    tile[l4 + 3][c] = bf16_rne(v.w);
  }
  __syncthreads();
  u16* op = xT + ((size_t)b * Ln + lt * 64) * Cn + ct * 64;
  for (int pass = 0; pass < 2; ++pass) {
    int id = pass * 256 + t;
    int l = id >> 3, c8 = (id & 7) * 8;
    *(uint4*)(op + (size_t)l * Cn + c8) = *(const uint4*)&tile[l][c8];
  }
}

// ---------------- QKV GEMM: qkv = wq[1536x256] @ x[b][256x2048] --------------
// Epilogue repacks through LDS -> coalesced uint4 global stores.
__global__ __launch_bounds__(256) void qkv_gemm(const u16* __restrict__ wq,
                                                const u16* __restrict__ xT,
                                                u16* __restrict__ qT,
                                                u16* __restrict__ kT,
                                                u16* __restrict__ vv) {
  __shared__ u16 As[4096];
  __shared__ u16 Bs[4096];
  const int t = threadIdx.x;
  const int nt = blockIdx.x, mt = blockIdx.y, b = blockIdx.z;
  const int m0 = mt * 64, n0 = nt * 64;
  const int w = t >> 6, lane = t & 63, q = lane >> 4, ln = lane & 15;

  const u16* Ag = wq + (size_t)m0 * Cn;
  const u16* Bg = xT + ((size_t)b * Ln + n0) * Cn;

  f32x4 zf = {0.f, 0.f, 0.f, 0.f};
  f32x4 acc[4];
  for (int i = 0; i < 4; ++i) acc[i] = zf;

  for (int kk = 0; kk < 4; ++kk) {
    int k0 = kk * 64;
    for (int k2 = 0; k2 < 2; ++k2) {
      int reg = k2 * 4 + w;
      int r = reg * 8 + (lane >> 3);
      int c = (lane & 7) ^ (r & 7);
      async_load16(Ag + (size_t)r * Cn + k0 + c * 8, &As[reg * 512]);
      async_load16(Bg + (size_t)r * Cn + k0 + c * 8, &Bs[reg * 512]);
    }
    __syncthreads();
    int ar = w * 16 + ln;
    bf16x8 a0 = *(const bf16x8*)&As[ar * 64 + ((q ^ (ln & 7)) * 8)];
    bf16x8 a1 = *(const bf16x8*)&As[ar * 64 + (((q + 4) ^ (ln & 7)) * 8)];
    for (int n2 = 0; n2 < 4; ++n2) {
      int br = n2 * 16 + ln;
      bf16x8 b0 = *(const bf16x8*)&Bs[br * 64 + ((q ^ (ln & 7)) * 8)];
      bf16x8 b1 = *(const bf16x8*)&Bs[br * 64 + (((q + 4) ^ (ln & 7)) * 8)];
      acc[n2] = MFMA16(a0, b0, acc[n2]);
      acc[n2] = MFMA16(a1, b1, acc[n2]);
    }
    __syncthreads();
  }

  // Epilogue via LDS repack (reuse As): value (l = n2*16+ln, od = w*16+q*4+r)
  if (mt < 16) {
    // Q/K transposed layout [b][h][l][64]: LDS [l][od] xor-swizzled, b64 over r
    int od0 = w * 16 + q * 4;
    int cw = od0 >> 3, lo = od0 & 7;
    for (int n2 = 0; n2 < 4; ++n2) {
      int l = n2 * 16 + ln;
      uint2 pk;
      pk.x = pack2(acc[n2][0], acc[n2][1]);
      pk.y = pack2(acc[n2][2], acc[n2][3]);
      *(uint2*)&As[l * 64 + ((cw ^ (l & 7)) * 8) + lo] = pk;
    }
    __syncthreads();
    u16* dst = (mt < 8) ? qT + (((size_t)b * Hn + mt) * Ln + n0) * Dn
                        : kT + (((size_t)b * Hn + (mt - 8)) * Ln + n0) * Dn;
    for (int pass = 0; pass < 2; ++pass) {
      int id = pass * 256 + t;
      int l = id >> 3, c = id & 7;
      *(uint4*)(dst + (size_t)l * Dn + c * 8) =
          *(const uint4*)&As[l * 64 + ((c ^ (l & 7)) * 8)];
    }
  } else {
    // V natural [b][512][l]: LDS [od][l] xor-swizzled, scalar writes
    for (int n2 = 0; n2 < 4; ++n2) {
      int l = n2 * 16 + ln;
      int cl = l >> 3, lo = l & 7;
      for (int r = 0; r < 4; ++r) {
        int od = w * 16 + q * 4 + r;
        As[od * 64 + ((cl ^ (od & 7)) * 8) + lo] = bf16_rne(acc[n2][r]);
      }
    }
    __syncthreads();
    u16* dst = vv + ((size_t)b * HID + (mt - 16) * 64) * Ln + n0;
    for (int pass = 0; pass < 2; ++pass) {
      int id = pass * 256 + t;
      int od = id >> 3, c = id & 7;
      *(uint4*)(dst + (size_t)od * Ln + c * 8) =
          *(const uint4*)&As[od * 64 + ((c ^ (od & 7)) * 8)];
    }
  }
}

// ---------------- Flash attention v3: reg-prefetch pipeline ------------------
// 128 q/block, 32 q/wave, BK=64. K/V for jt+1 loaded to VGPRs during compute(jt).
__global__ __launch_bounds__(256) void attention(const u16* __restrict__ qT,
                                                 const u16* __restrict__ kT,
                                                 const u16* __restrict__ vv,
                                                 u16* __restrict__ attT) {
  __shared__ u16 Kt[4096];  // [64 j][64 d] xor-swizzled chunks
  __shared__ u16 Vt[4096];  // [64 d][64 j] xor-swizzled chunks
  __shared__ u16 Ps[8192];  // per-wave 2x [16 i][64 j] swizzled
  const int t = threadIdx.x;
  const int qb = blockIdx.x, bh = blockIdx.y;
  const int b = bh >> 3, h = bh & 7;
  const int w = t >> 6, lane = t & 63, q = lane >> 4, ln = lane & 15;
  const int i0 = qb * 128 + w * 32;

  bf16x8 qa[2][2];
  for (int it = 0; it < 2; ++it) {
    const u16* qrow = qT + (((size_t)bh) * Ln + i0 + it * 16 + ln) * Dn;
    qa[it][0] = *(const bf16x8*)(qrow + q * 8);
    qa[it][1] = *(const bf16x8*)(qrow + 32 + q * 8);
  }

  const u16* ksrc0 = kT + ((size_t)bh) * Ln * Dn;
  const u16* vsrc0 = vv + ((size_t)b * HID + h * Dn) * Ln;

  bf16x8 ones;
  for (int i = 0; i < 8; ++i) ones[i] = (__bf16)1.0f;

  f32x4 zf = {0.f, 0.f, 0.f, 0.f};
  f32x4 o_acc[2][4], l_acc[2];
  for (int it = 0; it < 2; ++it) {
    l_acc[it] = zf;
    for (int d = 0; d < 4; ++d) o_acc[it][d] = zf;
  }
  u16* pw0 = Ps + w * 2048;

  // prefetch addressing: region reg = k2*4+w, row r = reg*8+(lane>>3),
  // chunk c = (lane&7)^(r&7); LDS dest reg*512+lane*8 == r*64+(c^(r&7))*8.
  const int pr0 = w * 8 + (lane >> 3), pr1 = (4 + w) * 8 + (lane >> 3);
  const int pc0 = (lane & 7) ^ (pr0 & 7), pc1 = (lane & 7) ^ (pr1 & 7);

  auto loadKV = [&](int jt, uint4* kr, uint4* vr) {
    int j0 = jt * 64;
    kr[0] = *(const uint4*)(ksrc0 + (size_t)(j0 + pr0) * Dn + pc0 * 8);
    kr[1] = *(const uint4*)(ksrc0 + (size_t)(j0 + pr1) * Dn + pc1 * 8);
    vr[0] = *(const uint4*)(vsrc0 + (size_t)pr0 * Ln + j0 + pc0 * 8);
    vr[1] = *(const uint4*)(vsrc0 + (size_t)pr1 * Ln + j0 + pc1 * 8);
  };
  auto storeKV = [&](const uint4* kr, const uint4* vr) {
    *(uint4*)&Kt[w * 512 + lane * 8] = kr[0];
    *(uint4*)&Kt[(4 + w) * 512 + lane * 8] = kr[1];
    *(uint4*)&Vt[w * 512 + lane * 8] = vr[0];
    *(uint4*)&Vt[(4 + w) * 512 + lane * 8] = vr[1];
  };

  auto compute = [&]() {
    f32x4 sv[2][4];
    for (int n2 = 0; n2 < 4; ++n2) {
      int jr = n2 * 16 + ln;
      bf16x8 k0f = *(const bf16x8*)&Kt[jr * 64 + ((q ^ (ln & 7)) * 8)];
      bf16x8 k1f = *(const bf16x8*)&Kt[jr * 64 + (((q + 4) ^ (ln & 7)) * 8)];
      for (int it = 0; it < 2; ++it) {
        f32x4 s = zf;
        s = MFMA16(k0f, qa[it][0], s);
        s = MFMA16(k1f, qa[it][1], s);
        sv[it][n2] = s;
      }
    }
    for (int it = 0; it < 2; ++it) {
      u16* pw = pw0 + it * 1024;
      for (int n2 = 0; n2 < 4; ++n2) {
        uint2 pk;
        pk.x = pack2(fast_exp2(sv[it][n2][0]), fast_exp2(sv[it][n2][1]));
        pk.y = pack2(fast_exp2(sv[it][n2][2]), fast_exp2(sv[it][n2][3]));
        int jw = n2 * 16 + q * 4;
        int c = jw >> 3, lo = jw & 7;
        *(uint2*)&pw[ln * 64 + ((c ^ (ln & 7)) * 8) + lo] = pk;
      }
    }
    for (int it = 0; it < 2; ++it) {
      u16* pw = pw0 + it * 1024;
      bf16x8 pa0 = *(const bf16x8*)&pw[ln * 64 + ((q ^ (ln & 7)) * 8)];
      bf16x8 pa1 = *(const bf16x8*)&pw[ln * 64 + (((q + 4) ^ (ln & 7)) * 8)];
      l_acc[it] = MFMA16(pa0, ones, l_acc[it]);
      l_acc[it] = MFMA16(pa1, ones, l_acc[it]);
      for (int d2 = 0; d2 < 4; ++d2) {
        int dr = d2 * 16 + ln;
        bf16x8 v0f = *(const bf16x8*)&Vt[dr * 64 + ((q ^ (ln & 7)) * 8)];
        bf16x8 v1f = *(const bf16x8*)&Vt[dr * 64 + (((q + 4) ^ (ln & 7)) * 8)];
        o_acc[it][d2] = MFMA16(pa0, v0f, o_acc[it][d2]);
        o_acc[it][d2] = MFMA16(pa1, v1f, o_acc[it][d2]);
      }
    }
  };

  uint4 ka[2], va[2], kb[2], vb[2];
  loadKV(0, ka, va);
  for (int jt = 0; jt < 32; jt += 2) {
    if (jt) __syncthreads();
    storeKV(ka, va);
    __syncthreads();
    loadKV(jt + 1, kb, vb);   // hides behind compute(jt)
    compute();
    __syncthreads();
    storeKV(kb, vb);
    __syncthreads();
    if (jt + 2 < 32) loadKV(jt + 2, ka, va);  // hides behind compute(jt+1)
    compute();
  }

  for (int it = 0; it < 2; ++it) {
    for (int r = 0; r < 4; ++r) {
      float rinv = fast_rcp(l_acc[it][r]);
      int i = i0 + it * 16 + q * 4 + r;
      size_t base = ((size_t)b * Ln + i) * HID + h * Dn;
      for (int d2 = 0; d2 < 4; ++d2)
        attT[base + d2 * 16 + ln] = bf16_rne(o_acc[it][d2][r] * rinv);
    }
  }
}

// ---------------- out GEMM: y = wo[256x512] @ att[b][512x2048] + b_out -------
// Same reg-prefetch pipeline (2 blocks/CU — needs in-block latency hiding).
__global__ __launch_bounds__(256) void out_gemm(const u16* __restrict__ wo,
                                                const u16* __restrict__ attT,
                                                const float* __restrict__ bout,
                                                float* __restrict__ out) {
  __shared__ u16 As[4096];
  __shared__ u16 Bs[4096];
  const int t = threadIdx.x;
  const int nt = blockIdx.x, mt = blockIdx.y, b = blockIdx.z;
  const int m0 = mt * 64, n0 = nt * 64;
  const int w = t >> 6, lane = t & 63, q = lane >> 4, ln = lane & 15;

  const u16* Ag = wo + (size_t)m0 * HID;
  const u16* Bg = attT + ((size_t)b * Ln + n0) * HID;

  f32x4 zf = {0.f, 0.f, 0.f, 0.f};
  f32x4 acc[4];
  for (int i = 0; i < 4; ++i) acc[i] = zf;

  const int pr0 = w * 8 + (lane >> 3), pr1 = (4 + w) * 8 + (lane >> 3);
  const int pc0 = (lane & 7) ^ (pr0 & 7), pc1 = (lane & 7) ^ (pr1 & 7);

  auto loadAB = [&](int kk, uint4* ar, uint4* br) {
    int k0 = kk * 64;
    ar[0] = *(const uint4*)(Ag + (size_t)pr0 * HID + k0 + pc0 * 8);
    ar[1] = *(const uint4*)(Ag + (size_t)pr1 * HID + k0 + pc1 * 8);
    br[0] = *(const uint4*)(Bg + (size_t)pr0 * HID + k0 + pc0 * 8);
    br[1] = *(const uint4*)(Bg + (size_t)pr1 * HID + k0 + pc1 * 8);
  };
  auto storeAB = [&](const uint4* ar, const uint4* br) {
    *(uint4*)&As[w * 512 + lane * 8] = ar[0];
    *(uint4*)&As[(4 + w) * 512 + lane * 8] = ar[1];
    *(uint4*)&Bs[w * 512 + lane * 8] = br[0];
    *(uint4*)&Bs[(4 + w) * 512 + lane * 8] = br[1];
  };
  auto computeC = [&]() {
    int ar = w * 16 + ln;
    bf16x8 a0 = *(const bf16x8*)&As[ar * 64 + ((q ^ (ln & 7)) * 8)];
    bf16x8 a1 = *(const bf16x8*)&As[ar * 64 + (((q + 4) ^ (ln & 7)) * 8)];
    for (int n2 = 0; n2 < 4; ++n2) {
      int br = n2 * 16 + ln;
      bf16x8 b0 = *(const bf16x8*)&Bs[br * 64 + ((q ^ (ln & 7)) * 8)];
      bf16x8 b1 = *(const bf16x8*)&Bs[br * 64 + (((q + 4) ^ (ln & 7)) * 8)];
      acc[n2] = MFMA16(a0, b0, acc[n2]);
      acc[n2] = MFMA16(a1, b1, acc[n2]);
    }
  };

  uint4 aa[2], ba[2], ab[2], bb[2];
  loadAB(0, aa, ba);
  for (int kk = 0; kk < 8; kk += 2) {
    if (kk) __syncthreads();
    storeAB(aa, ba);
    __syncthreads();
    loadAB(kk + 1, ab, bb);
    computeC();
    __syncthreads();
    storeAB(ab, bb);
    __syncthreads();
    if (kk + 2 < 8) loadAB(kk + 2, aa, ba);
    computeC();
  }

  float bias[4];
  for (int r = 0; r < 4; ++r) bias[r] = bout[m0 + w * 16 + q * 4 + r];
  for (int n2 = 0; n2 < 4; ++n2) {
    int l = n0 + n2 * 16 + ln;
    for (int r = 0; r < 4; ++r) {
      int o = m0 + w * 16 + q * 4 + r;
      out[((size_t)b * Cn + o) * Ln + l] = acc[n2][r] + bias[r];
    }
  }
}

// ---------------- launch -----------------------------------------------------
extern "C" void kernel_launch(void* const* d_in, const int* in_sizes, int n_in,
                              void* d_out, int out_size, void* d_ws, size_t ws_size,
                              hipStream_t stream) {
  const float* x = (const float*)d_in[0];
  const float* wqkv = (const float*)d_in[1];
  const float* wout = (const float*)d_in[2];
  const float* bout = (const float*)d_in[3];
  float* out = (float*)d_out;
  char* ws = (char*)d_ws;

  u16* wq_b = (u16*)(ws + 0);          // [1536][256] bf16
  u16* wo_b = (u16*)(ws + 786432);     // [256][512]  bf16
  u16* xT   = (u16*)(ws + 1048576);    // [4][2048][256]
  u16* qT   = (u16*)(ws + 5242880);    // [4][8][2048][64]
  u16* kT   = (u16*)(ws + 13631488);   // [4][8][2048][64]
  u16* vv   = (u16*)(ws + 22020096);   // [4][512][2048]
  u16* attT = (u16*)(ws + 30408704);   // [4][2048][512]

  prep_weights<<<2048, 256, 0, stream>>>(wqkv, wout, wq_b, wo_b);
  transpose_x<<<dim3(32, 4, 4), 256, 0, stream>>>(x, xT);
  qkv_gemm<<<dim3(32, 24, 4), 256, 0, stream>>>(wq_b, xT, qT, kT, vv);
  attention<<<dim3(16, 32), 256, 0, stream>>>(qT, kT, vv, attT);
  out_gemm<<<dim3(32, 4, 4), 256, 0, stream>>>(wo_b, attT, bout, out);
}

// Round 4
// 153.293 us; speedup vs baseline: 1.2919x; 1.2919x over previous
//
#include <hip/hip_runtime.h>

typedef unsigned short u16;
typedef __bf16 bf16x8 __attribute__((ext_vector_type(8)));
typedef float f32x4 __attribute__((ext_vector_type(4)));

#define MFMA16(a, b, c) __builtin_amdgcn_mfma_f32_16x16x32_bf16((a), (b), (c), 0, 0, 0)

// Problem constants
#define Bn 4
#define Cn 256
#define Ln 2048
#define Hn 8
#define Dn 64
#define HID 512

__device__ __forceinline__ u16 bf16_rne(float f) {
  unsigned u = __builtin_bit_cast(unsigned, f);
  u += 0x7FFFu + ((u >> 16) & 1u);
  return (u16)(u >> 16);
}

__device__ __forceinline__ unsigned pack2(float a, float b) {
  return (unsigned)bf16_rne(a) | ((unsigned)bf16_rne(b) << 16);
}

__device__ __forceinline__ float fast_exp2(float x) {
#if __has_builtin(__builtin_amdgcn_exp2f)
  return __builtin_amdgcn_exp2f(x);
#else
  return exp2f(x);
#endif
}

__device__ __forceinline__ float fast_rcp(float x) {
#if __has_builtin(__builtin_amdgcn_rcpf)
  return __builtin_amdgcn_rcpf(x);
#else
  return 1.0f / x;
#endif
}

// async 16B global -> LDS DMA. HW dest = wave-uniform base + lane*16.
__device__ __forceinline__ void async_load16(const u16* g, u16* l) {
  __builtin_amdgcn_global_load_lds(
      (const __attribute__((address_space(1))) void*)g,
      (__attribute__((address_space(3))) void*)l, 16, 0, 0);
}

// ---------------- prep: weights -> bf16 (q rows pre-scaled by 0.125*log2e) ---
__global__ __launch_bounds__(256) void prep_weights(const float* __restrict__ wqkv,
                                                    const float* __restrict__ wout,
                                                    u16* __restrict__ wq,
                                                    u16* __restrict__ wo) {
  int i = blockIdx.x * 256 + threadIdx.x;
  const float QSCALE = 0.125f * 1.44269504088896340736f;  // scale * log2(e)
  if (i < 3 * HID * Cn) {
    float v = wqkv[i];
    if (i < HID * Cn) v *= QSCALE;  // q rows
    wq[i] = bf16_rne(v);
  } else {
    int j = i - 3 * HID * Cn;
    wo[j] = bf16_rne(wout[j]);
  }
}

// ---------------- prep: x [b][256][2048] fp32 -> xT [b][2048][256] bf16 ------
__global__ __launch_bounds__(256) void transpose_x(const float* __restrict__ x,
                                                   u16* __restrict__ xT) {
  __shared__ u16 tile[64][72];
  const int b = blockIdx.z, ct = blockIdx.y, lt = blockIdx.x;
  const int t = threadIdx.x;
  const float* xp = x + ((size_t)b * Cn + ct * 64) * Ln + lt * 64;
  for (int pass = 0; pass < 4; ++pass) {
    int c = pass * 16 + (t >> 4);
    int l4 = (t & 15) * 4;
    float4 v = *(const float4*)(xp + (size_t)c * Ln + l4);
    tile[l4 + 0][c] = bf16_rne(v.x);
    tile[l4 + 1][c] = bf16_rne(v.y);
    tile[l4 + 2][c] = bf16_rne(v.z);
    tile[l4 + 3][c] = bf16_rne(v.w);
  }
  __syncthreads();
  u16* op = xT + ((size_t)b * Ln + lt * 64) * Cn + ct * 64;
  for (int pass = 0; pass < 2; ++pass) {
    int id = pass * 256 + t;
    int l = id >> 3, c8 = (id & 7) * 8;
    *(uint4*)(op + (size_t)l * Cn + c8) = *(const uint4*)&tile[l][c8];
  }
}

// ---------------- QKV GEMM: qkv = wq[1536x256] @ x[b][256x2048] --------------
__global__ __launch_bounds__(256) void qkv_gemm(const u16* __restrict__ wq,
                                                const u16* __restrict__ xT,
                                                u16* __restrict__ qT,
                                                u16* __restrict__ kT,
                                                u16* __restrict__ vv) {
  __shared__ u16 As[4096];
  __shared__ u16 Bs[4096];
  const int t = threadIdx.x;
  const int nt = blockIdx.x, mt = blockIdx.y, b = blockIdx.z;
  const int m0 = mt * 64, n0 = nt * 64;
  const int w = t >> 6, lane = t & 63, q = lane >> 4, ln = lane & 15;

  const u16* Ag = wq + (size_t)m0 * Cn;
  const u16* Bg = xT + ((size_t)b * Ln + n0) * Cn;

  f32x4 zf = {0.f, 0.f, 0.f, 0.f};
  f32x4 acc[4];
  for (int i = 0; i < 4; ++i) acc[i] = zf;

  for (int kk = 0; kk < 4; ++kk) {
    int k0 = kk * 64;
    for (int k2 = 0; k2 < 2; ++k2) {
      int reg = k2 * 4 + w;
      int r = reg * 8 + (lane >> 3);
      int c = (lane & 7) ^ (r & 7);
      async_load16(Ag + (size_t)r * Cn + k0 + c * 8, &As[reg * 512]);
      async_load16(Bg + (size_t)r * Cn + k0 + c * 8, &Bs[reg * 512]);
    }
    __syncthreads();
    int ar = w * 16 + ln;
    bf16x8 a0 = *(const bf16x8*)&As[ar * 64 + ((q ^ (ln & 7)) * 8)];
    bf16x8 a1 = *(const bf16x8*)&As[ar * 64 + (((q + 4) ^ (ln & 7)) * 8)];
    for (int n2 = 0; n2 < 4; ++n2) {
      int br = n2 * 16 + ln;
      bf16x8 b0 = *(const bf16x8*)&Bs[br * 64 + ((q ^ (ln & 7)) * 8)];
      bf16x8 b1 = *(const bf16x8*)&Bs[br * 64 + (((q + 4) ^ (ln & 7)) * 8)];
      acc[n2] = MFMA16(a0, b0, acc[n2]);
      acc[n2] = MFMA16(a1, b1, acc[n2]);
    }
    __syncthreads();
  }

  // Epilogue via LDS repack (reuse As): value (l = n2*16+ln, od = w*16+q*4+r)
  if (mt < 16) {
    int od0 = w * 16 + q * 4;
    int cw = od0 >> 3, lo = od0 & 7;
    for (int n2 = 0; n2 < 4; ++n2) {
      int l = n2 * 16 + ln;
      uint2 pk;
      pk.x = pack2(acc[n2][0], acc[n2][1]);
      pk.y = pack2(acc[n2][2], acc[n2][3]);
      *(uint2*)&As[l * 64 + ((cw ^ (l & 7)) * 8) + lo] = pk;
    }
    __syncthreads();
    u16* dst = (mt < 8) ? qT + (((size_t)b * Hn + mt) * Ln + n0) * Dn
                        : kT + (((size_t)b * Hn + (mt - 8)) * Ln + n0) * Dn;
    for (int pass = 0; pass < 2; ++pass) {
      int id = pass * 256 + t;
      int l = id >> 3, c = id & 7;
      *(uint4*)(dst + (size_t)l * Dn + c * 8) =
          *(const uint4*)&As[l * 64 + ((c ^ (l & 7)) * 8)];
    }
  } else {
    for (int n2 = 0; n2 < 4; ++n2) {
      int l = n2 * 16 + ln;
      int cl = l >> 3, lo = l & 7;
      for (int r = 0; r < 4; ++r) {
        int od = w * 16 + q * 4 + r;
        As[od * 64 + ((cl ^ (od & 7)) * 8) + lo] = bf16_rne(acc[n2][r]);
      }
    }
    __syncthreads();
    u16* dst = vv + ((size_t)b * HID + (mt - 16) * 64) * Ln + n0;
    for (int pass = 0; pass < 2; ++pass) {
      int id = pass * 256 + t;
      int od = id >> 3, c = id & 7;
      *(uint4*)(dst + (size_t)od * Ln + c * 8) =
          *(const uint4*)&As[od * 64 + ((c ^ (od & 7)) * 8)];
    }
  }
}

// ---------------- Flash attention v4: reg-prefetch pipeline, spill-proof -----
// 128 q/block, 32 q/wave, BK=64. All pipeline regs are named scalars via
// macros (NEVER address-taken) — round 3's lambda/array version demoted the
// prefetch registers to scratch (WRITE_SIZE 8->230 MB).
__global__ __launch_bounds__(256) void attention(const u16* __restrict__ qT,
                                                 const u16* __restrict__ kT,
                                                 const u16* __restrict__ vv,
                                                 u16* __restrict__ attT) {
  __shared__ u16 Kt[4096];  // [64 j][64 d] xor-swizzled chunks
  __shared__ u16 Vt[4096];  // [64 d][64 j] xor-swizzled chunks
  __shared__ u16 Ps[8192];  // per-wave 2x [16 i][64 j] swizzled
  const int t = threadIdx.x;
  const int qb = blockIdx.x, bh = blockIdx.y;
  const int b = bh >> 3, h = bh & 7;
  const int w = t >> 6, lane = t & 63, q = lane >> 4, ln = lane & 15;
  const int i0 = qb * 128 + w * 32;

  bf16x8 qa00, qa01, qa10, qa11;
  {
    const u16* qrow0 = qT + (((size_t)bh) * Ln + i0 + ln) * Dn;
    const u16* qrow1 = qT + (((size_t)bh) * Ln + i0 + 16 + ln) * Dn;
    qa00 = *(const bf16x8*)(qrow0 + q * 8);
    qa01 = *(const bf16x8*)(qrow0 + 32 + q * 8);
    qa10 = *(const bf16x8*)(qrow1 + q * 8);
    qa11 = *(const bf16x8*)(qrow1 + 32 + q * 8);
  }

  const u16* ksrc0 = kT + ((size_t)bh) * Ln * Dn;
  const u16* vsrc0 = vv + ((size_t)b * HID + h * Dn) * Ln;

  bf16x8 ones;
  for (int i = 0; i < 8; ++i) ones[i] = (__bf16)1.0f;

  f32x4 zf = {0.f, 0.f, 0.f, 0.f};
  f32x4 o_acc[2][4], l_acc[2];
  for (int it = 0; it < 2; ++it) {
    l_acc[it] = zf;
    for (int d = 0; d < 4; ++d) o_acc[it][d] = zf;
  }
  u16* pw0 = Ps + w * 2048;

  const int pr0 = w * 8 + (lane >> 3), pr1 = (4 + w) * 8 + (lane >> 3);
  const int pc0 = (lane & 7) ^ (pr0 & 7), pc1 = (lane & 7) ^ (pr1 & 7);
  const u16* kadr0 = ksrc0 + (size_t)pr0 * Dn + pc0 * 8;
  const u16* kadr1 = ksrc0 + (size_t)pr1 * Dn + pc1 * 8;
  const u16* vadr0 = vsrc0 + (size_t)pr0 * Ln + pc0 * 8;
  const u16* vadr1 = vsrc0 + (size_t)pr1 * Ln + pc1 * 8;

#define LOADKV(jt, K0, K1, V0, V1)                              \
  {                                                             \
    int j0_ = (jt) * 64;                                        \
    K0 = *(const uint4*)(kadr0 + (size_t)j0_ * Dn);             \
    K1 = *(const uint4*)(kadr1 + (size_t)j0_ * Dn);             \
    V0 = *(const uint4*)(vadr0 + j0_);                          \
    V1 = *(const uint4*)(vadr1 + j0_);                          \
  }

#define STOREKV(K0, K1, V0, V1)                                 \
  {                                                             \
    *(uint4*)&Kt[w * 512 + lane * 8] = K0;                      \
    *(uint4*)&Kt[(4 + w) * 512 + lane * 8] = K1;                \
    *(uint4*)&Vt[w * 512 + lane * 8] = V0;                      \
    *(uint4*)&Vt[(4 + w) * 512 + lane * 8] = V1;                \
  }

#define COMPUTE()                                                              \
  {                                                                            \
    f32x4 sv[2][4];                                                            \
    for (int n2 = 0; n2 < 4; ++n2) {                                           \
      int jr = n2 * 16 + ln;                                                   \
      bf16x8 k0f = *(const bf16x8*)&Kt[jr * 64 + ((q ^ (ln & 7)) * 8)];        \
      bf16x8 k1f = *(const bf16x8*)&Kt[jr * 64 + (((q + 4) ^ (ln & 7)) * 8)];  \
      f32x4 s0 = zf, s1 = zf;                                                  \
      s0 = MFMA16(k0f, qa00, s0);                                              \
      s0 = MFMA16(k1f, qa01, s0);                                              \
      s1 = MFMA16(k0f, qa10, s1);                                              \
      s1 = MFMA16(k1f, qa11, s1);                                              \
      sv[0][n2] = s0;                                                          \
      sv[1][n2] = s1;                                                          \
    }                                                                          \
    for (int it = 0; it < 2; ++it) {                                           \
      u16* pw = pw0 + it * 1024;                                               \
      for (int n2 = 0; n2 < 4; ++n2) {                                         \
        uint2 pk;                                                              \
        pk.x = pack2(fast_exp2(sv[it][n2][0]), fast_exp2(sv[it][n2][1]));      \
        pk.y = pack2(fast_exp2(sv[it][n2][2]), fast_exp2(sv[it][n2][3]));      \
        int jw = n2 * 16 + q * 4;                                              \
        int c_ = jw >> 3, lo_ = jw & 7;                                        \
        *(uint2*)&pw[ln * 64 + ((c_ ^ (ln & 7)) * 8) + lo_] = pk;              \
      }                                                                        \
    }                                                                          \
    for (int it = 0; it < 2; ++it) {                                           \
      u16* pw = pw0 + it * 1024;                                               \
      bf16x8 pa0 = *(const bf16x8*)&pw[ln * 64 + ((q ^ (ln & 7)) * 8)];        \
      bf16x8 pa1 = *(const bf16x8*)&pw[ln * 64 + (((q + 4) ^ (ln & 7)) * 8)];  \
      l_acc[it] = MFMA16(pa0, ones, l_acc[it]);                                \
      l_acc[it] = MFMA16(pa1, ones, l_acc[it]);                                \
      for (int d2 = 0; d2 < 4; ++d2) {                                         \
        int dr = d2 * 16 + ln;                                                 \
        bf16x8 v0f = *(const bf16x8*)&Vt[dr * 64 + ((q ^ (ln & 7)) * 8)];      \
        bf16x8 v1f = *(const bf16x8*)&Vt[dr * 64 + (((q + 4) ^ (ln & 7)) * 8)];\
        o_acc[it][d2] = MFMA16(pa0, v0f, o_acc[it][d2]);                       \
        o_acc[it][d2] = MFMA16(pa1, v1f, o_acc[it][d2]);                       \
      }                                                                        \
    }                                                                          \
  }

  uint4 ka0, ka1, wa0, wa1, kb0, kb1, wb0, wb1;
  LOADKV(0, ka0, ka1, wa0, wa1);
  for (int jt = 0; jt < 32; jt += 2) {
    if (jt) __syncthreads();
    STOREKV(ka0, ka1, wa0, wa1);
    __syncthreads();
    LOADKV(jt + 1, kb0, kb1, wb0, wb1);  // hides behind COMPUTE(jt)
    COMPUTE();
    __syncthreads();
    STOREKV(kb0, kb1, wb0, wb1);
    __syncthreads();
    if (jt + 2 < 32) LOADKV(jt + 2, ka0, ka1, wa0, wa1);
    COMPUTE();
  }
#undef LOADKV
#undef STOREKV
#undef COMPUTE

  for (int it = 0; it < 2; ++it) {
    for (int r = 0; r < 4; ++r) {
      float rinv = fast_rcp(l_acc[it][r]);
      int i = i0 + it * 16 + q * 4 + r;
      size_t base = ((size_t)b * Ln + i) * HID + h * Dn;
      for (int d2 = 0; d2 < 4; ++d2)
        attT[base + d2 * 16 + ln] = bf16_rne(o_acc[it][d2][r] * rinv);
    }
  }
}

// ---------------- out GEMM: y = wo[256x512] @ att[b][512x2048] + b_out -------
// Reg-prefetch pipeline, spill-proof (named scalars via macros).
__global__ __launch_bounds__(256) void out_gemm(const u16* __restrict__ wo,
                                                const u16* __restrict__ attT,
                                                const float* __restrict__ bout,
                                                float* __restrict__ out) {
  __shared__ u16 As[4096];
  __shared__ u16 Bs[4096];
  const int t = threadIdx.x;
  const int nt = blockIdx.x, mt = blockIdx.y, b = blockIdx.z;
  const int m0 = mt * 64, n0 = nt * 64;
  const int w = t >> 6, lane = t & 63, q = lane >> 4, ln = lane & 15;

  const u16* Ag = wo + (size_t)m0 * HID;
  const u16* Bg = attT + ((size_t)b * Ln + n0) * HID;

  f32x4 zf = {0.f, 0.f, 0.f, 0.f};
  f32x4 acc[4];
  for (int i = 0; i < 4; ++i) acc[i] = zf;

  const int pr0 = w * 8 + (lane >> 3), pr1 = (4 + w) * 8 + (lane >> 3);
  const int pc0 = (lane & 7) ^ (pr0 & 7), pc1 = (lane & 7) ^ (pr1 & 7);
  const u16* Aad0 = Ag + (size_t)pr0 * HID + pc0 * 8;
  const u16* Aad1 = Ag + (size_t)pr1 * HID + pc1 * 8;
  const u16* Bad0 = Bg + (size_t)pr0 * HID + pc0 * 8;
  const u16* Bad1 = Bg + (size_t)pr1 * HID + pc1 * 8;

#define LOADAB(kk, A0, A1, B0, B1)               \
  {                                              \
    int k0_ = (kk) * 64;                         \
    A0 = *(const uint4*)(Aad0 + k0_);            \
    A1 = *(const uint4*)(Aad1 + k0_);            \
    B0 = *(const uint4*)(Bad0 + k0_);            \
    B1 = *(const uint4*)(Bad1 + k0_);            \
  }

#define STOREAB(A0, A1, B0, B1)                  \
  {                                              \
    *(uint4*)&As[w * 512 + lane * 8] = A0;       \
    *(uint4*)&As[(4 + w) * 512 + lane * 8] = A1; \
    *(uint4*)&Bs[w * 512 + lane * 8] = B0;       \
    *(uint4*)&Bs[(4 + w) * 512 + lane * 8] = B1; \
  }

#define COMPUTEC()                                                             \
  {                                                                            \
    int ar = w * 16 + ln;                                                      \
    bf16x8 a0 = *(const bf16x8*)&As[ar * 64 + ((q ^ (ln & 7)) * 8)];           \
    bf16x8 a1 = *(const bf16x8*)&As[ar * 64 + (((q + 4) ^ (ln & 7)) * 8)];     \
    for (int n2 = 0; n2 < 4; ++n2) {                                           \
      int br = n2 * 16 + ln;                                                   \
      bf16x8 b0 = *(const bf16x8*)&Bs[br * 64 + ((q ^ (ln & 7)) * 8)];         \
      bf16x8 b1 = *(const bf16x8*)&Bs[br * 64 + (((q + 4) ^ (ln & 7)) * 8)];   \
      acc[n2] = MFMA16(a0, b0, acc[n2]);                                       \
      acc[n2] = MFMA16(a1, b1, acc[n2]);                                       \
    }                                                                          \
  }

  uint4 aa0, aa1, ba0, ba1, ab0, ab1, bb0, bb1;
  LOADAB(0, aa0, aa1, ba0, ba1);
  for (int kk = 0; kk < 8; kk += 2) {
    if (kk) __syncthreads();
    STOREAB(aa0, aa1, ba0, ba1);
    __syncthreads();
    LOADAB(kk + 1, ab0, ab1, bb0, bb1);
    COMPUTEC();
    __syncthreads();
    STOREAB(ab0, ab1, bb0, bb1);
    __syncthreads();
    if (kk + 2 < 8) LOADAB(kk + 2, aa0, aa1, ba0, ba1);
    COMPUTEC();
  }
#undef LOADAB
#undef STOREAB
#undef COMPUTEC

  float bias[4];
  for (int r = 0; r < 4; ++r) bias[r] = bout[m0 + w * 16 + q * 4 + r];
  for (int n2 = 0; n2 < 4; ++n2) {
    int l = n0 + n2 * 16 + ln;
    for (int r = 0; r < 4; ++r) {
      int o = m0 + w * 16 + q * 4 + r;
      out[((size_t)b * Cn + o) * Ln + l] = acc[n2][r] + bias[r];
    }
  }
}

// ---------------- launch -----------------------------------------------------
extern "C" void kernel_launch(void* const* d_in, const int* in_sizes, int n_in,
                              void* d_out, int out_size, void* d_ws, size_t ws_size,
                              hipStream_t stream) {
  const float* x = (const float*)d_in[0];
  const float* wqkv = (const float*)d_in[1];
  const float* wout = (const float*)d_in[2];
  const float* bout = (const float*)d_in[3];
  float* out = (float*)d_out;
  char* ws = (char*)d_ws;

  u16* wq_b = (u16*)(ws + 0);          // [1536][256] bf16
  u16* wo_b = (u16*)(ws + 786432);     // [256][512]  bf16
  u16* xT   = (u16*)(ws + 1048576);    // [4][2048][256]
  u16* qT   = (u16*)(ws + 5242880);    // [4][8][2048][64]
  u16* kT   = (u16*)(ws + 13631488);   // [4][8][2048][64]
  u16* vv   = (u16*)(ws + 22020096);   // [4][512][2048]
  u16* attT = (u16*)(ws + 30408704);   // [4][2048][512]

  prep_weights<<<2048, 256, 0, stream>>>(wqkv, wout, wq_b, wo_b);
  transpose_x<<<dim3(32, 4, 4), 256, 0, stream>>>(x, xT);
  qkv_gemm<<<dim3(32, 24, 4), 256, 0, stream>>>(wq_b, xT, qT, kT, vv);
  attention<<<dim3(16, 32), 256, 0, stream>>>(qT, kT, vv, attT);
  out_gemm<<<dim3(32, 4, 4), 256, 0, stream>>>(wo_b, attT, bout, out);
}

// Round 5
// 142.563 us; speedup vs baseline: 1.3891x; 1.0753x over previous
//
#include <hip/hip_runtime.h>

typedef unsigned short u16;
typedef unsigned int u32;
typedef __bf16 bf16x8 __attribute__((ext_vector_type(8)));
typedef float f32x4 __attribute__((ext_vector_type(4)));
typedef float f32x16 __attribute__((ext_vector_type(16)));

#define MFMA16(a, b, c) __builtin_amdgcn_mfma_f32_16x16x32_bf16((a), (b), (c), 0, 0, 0)
#define MFMA32(a, b, c) __builtin_amdgcn_mfma_f32_32x32x16_bf16((a), (b), (c), 0, 0, 0)

// Problem constants
#define Bn 4
#define Cn 256
#define Ln 2048
#define Hn 8
#define Dn 64
#define HID 512

__device__ __forceinline__ u16 bf16_rne(float f) {
  u32 u = __builtin_bit_cast(u32, f);
  u += 0x7FFFu + ((u >> 16) & 1u);
  return (u16)(u >> 16);
}

__device__ __forceinline__ unsigned pack2(float a, float b) {
  return (unsigned)bf16_rne(a) | ((unsigned)bf16_rne(b) << 16);
}

// cheap bf16 pack: round-half-up (+0x8000, keep hi16). lo -> bits[15:0].
__device__ __forceinline__ u32 pk_hi(float lo, float hi) {
  u32 a = __builtin_bit_cast(u32, lo) + 0x8000u;
  u32 b = __builtin_bit_cast(u32, hi) + 0x8000u;
  return (b & 0xFFFF0000u) | (a >> 16);
}

__device__ __forceinline__ float fast_exp2(float x) {
#if __has_builtin(__builtin_amdgcn_exp2f)
  return __builtin_amdgcn_exp2f(x);
#else
  return exp2f(x);
#endif
}

__device__ __forceinline__ float fast_rcp(float x) {
#if __has_builtin(__builtin_amdgcn_rcpf)
  return __builtin_amdgcn_rcpf(x);
#else
  return 1.0f / x;
#endif
}

// ---------------- prep (merged): weights->bf16 AND x transpose ---------------
__global__ __launch_bounds__(256) void prep_all(const float* __restrict__ wqkv,
                                                const float* __restrict__ wout,
                                                const float* __restrict__ x,
                                                u16* __restrict__ wq,
                                                u16* __restrict__ wo,
                                                u16* __restrict__ xT) {
  const int t = threadIdx.x;
  if (blockIdx.x < 2048) {
    int i = blockIdx.x * 256 + t;
    const float QSCALE = 0.125f * 1.44269504088896340736f;  // scale * log2(e)
    if (i < 3 * HID * Cn) {
      float v = wqkv[i];
      if (i < HID * Cn) v *= QSCALE;  // q rows
      wq[i] = bf16_rne(v);
    } else {
      int j = i - 3 * HID * Cn;
      wo[j] = bf16_rne(wout[j]);
    }
    return;
  }
  __shared__ u16 tile[64][72];
  int v = blockIdx.x - 2048;
  const int lt = v & 31, ct = (v >> 5) & 3, b = v >> 7;
  const float* xp = x + ((size_t)b * Cn + ct * 64) * Ln + lt * 64;
  for (int pass = 0; pass < 4; ++pass) {
    int c = pass * 16 + (t >> 4);
    int l4 = (t & 15) * 4;
    float4 vf = *(const float4*)(xp + (size_t)c * Ln + l4);
    tile[l4 + 0][c] = bf16_rne(vf.x);
    tile[l4 + 1][c] = bf16_rne(vf.y);
    tile[l4 + 2][c] = bf16_rne(vf.z);
    tile[l4 + 3][c] = bf16_rne(vf.w);
  }
  __syncthreads();
  u16* op = xT + ((size_t)b * Ln + lt * 64) * Cn + ct * 64;
  for (int pass = 0; pass < 2; ++pass) {
    int id = pass * 256 + t;
    int l = id >> 3, c8 = (id & 7) * 8;
    *(uint4*)(op + (size_t)l * Cn + c8) = *(const uint4*)&tile[l][c8];
  }
}

// ---------------- QKV GEMM: qkv = wq[1536x256] @ x[b][256x2048] --------------
// Reg-prefetch pipeline; epilogue repacks through LDS -> coalesced stores.
__global__ __launch_bounds__(256) void qkv_gemm(const u16* __restrict__ wq,
                                                const u16* __restrict__ xT,
                                                u16* __restrict__ qT,
                                                u16* __restrict__ kT,
                                                u16* __restrict__ vv) {
  __shared__ u16 As[4096];
  __shared__ u16 Bs[4096];
  const int t = threadIdx.x;
  const int nt = blockIdx.x, mt = blockIdx.y, b = blockIdx.z;
  const int m0 = mt * 64, n0 = nt * 64;
  const int w = t >> 6, lane = t & 63, q = lane >> 4, ln = lane & 15;

  const u16* Ag = wq + (size_t)m0 * Cn;
  const u16* Bg = xT + ((size_t)b * Ln + n0) * Cn;

  f32x4 zf = {0.f, 0.f, 0.f, 0.f};
  f32x4 acc[4];
  for (int i = 0; i < 4; ++i) acc[i] = zf;

  const int pr0 = w * 8 + (lane >> 3), pr1 = (4 + w) * 8 + (lane >> 3);
  const int pc0 = (lane & 7) ^ (pr0 & 7), pc1 = (lane & 7) ^ (pr1 & 7);
  const u16* Aad0 = Ag + (size_t)pr0 * Cn + pc0 * 8;
  const u16* Aad1 = Ag + (size_t)pr1 * Cn + pc1 * 8;
  const u16* Bad0 = Bg + (size_t)pr0 * Cn + pc0 * 8;
  const u16* Bad1 = Bg + (size_t)pr1 * Cn + pc1 * 8;

#define LOADAB(kk, A0, A1, B0, B1)               \
  {                                              \
    int k0_ = (kk) * 64;                         \
    A0 = *(const uint4*)(Aad0 + k0_);            \
    A1 = *(const uint4*)(Aad1 + k0_);            \
    B0 = *(const uint4*)(Bad0 + k0_);            \
    B1 = *(const uint4*)(Bad1 + k0_);            \
  }
#define STOREAB(A0, A1, B0, B1)                  \
  {                                              \
    *(uint4*)&As[w * 512 + lane * 8] = A0;       \
    *(uint4*)&As[(4 + w) * 512 + lane * 8] = A1; \
    *(uint4*)&Bs[w * 512 + lane * 8] = B0;       \
    *(uint4*)&Bs[(4 + w) * 512 + lane * 8] = B1; \
  }
#define COMPUTEC()                                                             \
  {                                                                            \
    int ar = w * 16 + ln;                                                      \
    bf16x8 a0 = *(const bf16x8*)&As[ar * 64 + ((q ^ (ln & 7)) * 8)];           \
    bf16x8 a1 = *(const bf16x8*)&As[ar * 64 + (((q + 4) ^ (ln & 7)) * 8)];     \
    for (int n2 = 0; n2 < 4; ++n2) {                                           \
      int br = n2 * 16 + ln;                                                   \
      bf16x8 b0 = *(const bf16x8*)&Bs[br * 64 + ((q ^ (ln & 7)) * 8)];         \
      bf16x8 b1 = *(const bf16x8*)&Bs[br * 64 + (((q + 4) ^ (ln & 7)) * 8)];   \
      acc[n2] = MFMA16(a0, b0, acc[n2]);                                       \
      acc[n2] = MFMA16(a1, b1, acc[n2]);                                       \
    }                                                                          \
  }

  uint4 aa0, aa1, ba0, ba1, ab0, ab1, bb0, bb1;
  LOADAB(0, aa0, aa1, ba0, ba1);
  for (int kk = 0; kk < 4; kk += 2) {
    if (kk) __syncthreads();
    STOREAB(aa0, aa1, ba0, ba1);
    __syncthreads();
    LOADAB(kk + 1, ab0, ab1, bb0, bb1);
    COMPUTEC();
    __syncthreads();
    STOREAB(ab0, ab1, bb0, bb1);
    __syncthreads();
    if (kk + 2 < 4) LOADAB(kk + 2, aa0, aa1, ba0, ba1);
    COMPUTEC();
  }
#undef LOADAB
#undef STOREAB
#undef COMPUTEC

  __syncthreads();
  // Epilogue via LDS repack (reuse As): value (l = n2*16+ln, od = w*16+q*4+r)
  if (mt < 16) {
    int od0 = w * 16 + q * 4;
    int cw = od0 >> 3, lo = od0 & 7;
    for (int n2 = 0; n2 < 4; ++n2) {
      int l = n2 * 16 + ln;
      uint2 pk;
      pk.x = pack2(acc[n2][0], acc[n2][1]);
      pk.y = pack2(acc[n2][2], acc[n2][3]);
      *(uint2*)&As[l * 64 + ((cw ^ (l & 7)) * 8) + lo] = pk;
    }
    __syncthreads();
    u16* dst = (mt < 8) ? qT + (((size_t)b * Hn + mt) * Ln + n0) * Dn
                        : kT + (((size_t)b * Hn + (mt - 8)) * Ln + n0) * Dn;
    for (int pass = 0; pass < 2; ++pass) {
      int id = pass * 256 + t;
      int l = id >> 3, c = id & 7;
      *(uint4*)(dst + (size_t)l * Dn + c * 8) =
          *(const uint4*)&As[l * 64 + ((c ^ (l & 7)) * 8)];
    }
  } else {
    for (int n2 = 0; n2 < 4; ++n2) {
      int l = n2 * 16 + ln;
      int cl = l >> 3, lo = l & 7;
      for (int r = 0; r < 4; ++r) {
        int od = w * 16 + q * 4 + r;
        As[od * 64 + ((cl ^ (od & 7)) * 8) + lo] = bf16_rne(acc[n2][r]);
      }
    }
    __syncthreads();
    u16* dst = vv + ((size_t)b * HID + (mt - 16) * 64) * Ln + n0;
    for (int pass = 0; pass < 2; ++pass) {
      int id = pass * 256 + t;
      int od = id >> 3, c = id & 7;
      *(uint4*)(dst + (size_t)od * Ln + c * 8) =
          *(const uint4*)&As[od * 64 + ((c ^ (od & 7)) * 8)];
    }
  }
}

// ---------------- Flash attention v5: 32x32x16 MFMA ---------------------------
// 128 q/block, 32 q/wave. S^T = MFMA32(A=K, B=Q): D col i = lane&31, rows j.
// exp2 (no max-shift), cheap half-up pack, l-rowsum in VALU (1 shuffle at end).
// P -> per-wave LDS [32 i][64 j] -> A-frags for O = MFMA32(A=P, B=V^T).
__global__ __launch_bounds__(256) void attention(const u16* __restrict__ qT,
                                                 const u16* __restrict__ kT,
                                                 const u16* __restrict__ vv,
                                                 u16* __restrict__ attT) {
  __shared__ u16 Kt[4096];  // [64 j][64 d], 16B chunk c stored at c^(j&7)
  __shared__ u16 Vt[4096];  // [64 d][64 j], chunk c at c^(d&7)
  __shared__ u16 Ps[8192];  // 4 waves x [32 i][64 j], chunk-swizzled
  const int t = threadIdx.x;
  const int qb = blockIdx.x, bh = blockIdx.y;
  const int b = bh >> 3, hh = bh & 7;
  const int w = t >> 6, lane = t & 63;
  const int li = lane & 31, h = lane >> 5;
  const int i0 = qb * 128 + w * 32;

  // Q B-frags: B[k=d][n=i]: lane holds Q[i0+li][c*16 + h*8 .. +8]
  bf16x8 qf0, qf1, qf2, qf3;
  {
    const u16* qrow = qT + (((size_t)bh) * Ln + i0 + li) * Dn + h * 8;
    qf0 = *(const bf16x8*)(qrow + 0);
    qf1 = *(const bf16x8*)(qrow + 16);
    qf2 = *(const bf16x8*)(qrow + 32);
    qf3 = *(const bf16x8*)(qrow + 48);
  }

  const u16* ksrc0 = kT + ((size_t)bh) * Ln * Dn;
  const u16* vsrc0 = vv + ((size_t)b * HID + hh * Dn) * Ln;

  f32x16 o0, o1;
#pragma unroll
  for (int r = 0; r < 16; ++r) { o0[r] = 0.f; o1[r] = 0.f; }
  float lp = 0.f;
  u16* pw = Ps + w * 2048;

  const int pr0 = w * 8 + (lane >> 3), pr1 = (4 + w) * 8 + (lane >> 3);
  const int pc0 = (lane & 7) ^ (pr0 & 7), pc1 = (lane & 7) ^ (pr1 & 7);
  const u16* kadr0 = ksrc0 + (size_t)pr0 * Dn + pc0 * 8;
  const u16* kadr1 = ksrc0 + (size_t)pr1 * Dn + pc1 * 8;
  const u16* vadr0 = vsrc0 + (size_t)pr0 * Ln + pc0 * 8;
  const u16* vadr1 = vsrc0 + (size_t)pr1 * Ln + pc1 * 8;

#define LOADKV(jt, K0, K1, V0, V1)                              \
  {                                                             \
    int j0_ = (jt) * 64;                                        \
    K0 = *(const uint4*)(kadr0 + (size_t)j0_ * Dn);             \
    K1 = *(const uint4*)(kadr1 + (size_t)j0_ * Dn);             \
    V0 = *(const uint4*)(vadr0 + j0_);                          \
    V1 = *(const uint4*)(vadr1 + j0_);                          \
  }
#define STOREKV(K0, K1, V0, V1)                                 \
  {                                                             \
    *(uint4*)&Kt[w * 512 + lane * 8] = K0;                      \
    *(uint4*)&Kt[(4 + w) * 512 + lane * 8] = K1;                \
    *(uint4*)&Vt[w * 512 + lane * 8] = V0;                      \
    *(uint4*)&Vt[(4 + w) * 512 + lane * 8] = V1;                \
  }

#define COMPUTE()                                                              \
  {                                                                            \
    f32x16 sv0, sv1;                                                           \
    _Pragma("unroll") for (int r = 0; r < 16; ++r) { sv0[r] = 0.f; sv1[r] = 0.f; } \
    _Pragma("unroll") for (int c = 0; c < 4; ++c) {                            \
      int ch = 2 * c + h;                                                      \
      bf16x8 k0 = *(const bf16x8*)&Kt[li * 64 + ((ch ^ (li & 7)) * 8)];        \
      bf16x8 k1 = *(const bf16x8*)&Kt[(32 + li) * 64 + ((ch ^ (li & 7)) * 8)]; \
      bf16x8 qc = (c == 0) ? qf0 : (c == 1) ? qf1 : (c == 2) ? qf2 : qf3;      \
      sv0 = MFMA32(k0, qc, sv0);                                               \
      sv1 = MFMA32(k1, qc, sv1);                                               \
    }                                                                          \
    _Pragma("unroll") for (int js = 0; js < 2; ++js) {                         \
      _Pragma("unroll") for (int g = 0; g < 4; ++g) {                          \
        float e0 = fast_exp2(js ? sv1[4 * g + 0] : sv0[4 * g + 0]);            \
        float e1 = fast_exp2(js ? sv1[4 * g + 1] : sv0[4 * g + 1]);            \
        float e2 = fast_exp2(js ? sv1[4 * g + 2] : sv0[4 * g + 2]);            \
        float e3 = fast_exp2(js ? sv1[4 * g + 3] : sv0[4 * g + 3]);            \
        lp += (e0 + e1) + (e2 + e3);                                           \
        uint2 pk;                                                              \
        pk.x = pk_hi(e0, e1);                                                  \
        pk.y = pk_hi(e2, e3);                                                  \
        int cjj = js * 4 + g;                                                  \
        *(uint2*)&pw[li * 64 + ((cjj ^ (li & 7)) * 8) + 4 * h] = pk;           \
      }                                                                        \
    }                                                                          \
    bf16x8 pf0 = *(const bf16x8*)&pw[li * 64 + (((2 * 0 + h) ^ (li & 7)) * 8)];\
    bf16x8 pf1 = *(const bf16x8*)&pw[li * 64 + (((2 * 1 + h) ^ (li & 7)) * 8)];\
    bf16x8 pf2 = *(const bf16x8*)&pw[li * 64 + (((2 * 2 + h) ^ (li & 7)) * 8)];\
    bf16x8 pf3 = *(const bf16x8*)&pw[li * 64 + (((2 * 3 + h) ^ (li & 7)) * 8)];\
    _Pragma("unroll") for (int jc = 0; jc < 4; ++jc) {                         \
      int ch = 2 * jc + h;                                                     \
      bf16x8 pf = (jc == 0) ? pf0 : (jc == 1) ? pf1 : (jc == 2) ? pf2 : pf3;   \
      bf16x8 vf0 = *(const bf16x8*)&Vt[li * 64 + ((ch ^ (li & 7)) * 8)];       \
      bf16x8 vf1 = *(const bf16x8*)&Vt[(32 + li) * 64 + ((ch ^ (li & 7)) * 8)];\
      o0 = MFMA32(pf, vf0, o0);                                                \
      o1 = MFMA32(pf, vf1, o1);                                                \
    }                                                                          \
  }

  uint4 ka0, ka1, wa0, wa1, kb0, kb1, wb0, wb1;
  LOADKV(0, ka0, ka1, wa0, wa1);
  for (int jt = 0; jt < 32; jt += 2) {
    if (jt) __syncthreads();
    STOREKV(ka0, ka1, wa0, wa1);
    __syncthreads();
    LOADKV(jt + 1, kb0, kb1, wb0, wb1);  // hides behind COMPUTE(jt)
    COMPUTE();
    __syncthreads();
    STOREKV(kb0, kb1, wb0, wb1);
    __syncthreads();
    if (jt + 2 < 32) LOADKV(jt + 2, ka0, ka1, wa0, wa1);
    COMPUTE();
  }
#undef LOADKV
#undef STOREKV
#undef COMPUTE

  // l[i]: lane li holds partial over its j-subset; partner lane li+32 the rest.
  float lsum = lp + __shfl_xor(lp, 32);
  float linv = fast_rcp(lsum);
#pragma unroll
  for (int r = 0; r < 16; ++r) {
    int ir = (r & 3) + 8 * (r >> 2) + 4 * h;  // row i of reg r
    float lv = __shfl(linv, ir);              // l-inverse for row ir (lane ir)
    size_t base = ((size_t)b * Ln + i0 + ir) * HID + hh * Dn + li;
    attT[base] = bf16_rne(o0[r] * lv);
    attT[base + 32] = bf16_rne(o1[r] * lv);
  }
}

// ---------------- out GEMM: y = wo[256x512] @ att[b][512x2048] + b_out -------
__global__ __launch_bounds__(256) void out_gemm(const u16* __restrict__ wo,
                                                const u16* __restrict__ attT,
                                                const float* __restrict__ bout,
                                                float* __restrict__ out) {
  __shared__ u16 As[4096];
  __shared__ u16 Bs[4096];
  const int t = threadIdx.x;
  const int nt = blockIdx.x, mt = blockIdx.y, b = blockIdx.z;
  const int m0 = mt * 64, n0 = nt * 64;
  const int w = t >> 6, lane = t & 63, q = lane >> 4, ln = lane & 15;

  const u16* Ag = wo + (size_t)m0 * HID;
  const u16* Bg = attT + ((size_t)b * Ln + n0) * HID;

  f32x4 zf = {0.f, 0.f, 0.f, 0.f};
  f32x4 acc[4];
  for (int i = 0; i < 4; ++i) acc[i] = zf;

  const int pr0 = w * 8 + (lane >> 3), pr1 = (4 + w) * 8 + (lane >> 3);
  const int pc0 = (lane & 7) ^ (pr0 & 7), pc1 = (lane & 7) ^ (pr1 & 7);
  const u16* Aad0 = Ag + (size_t)pr0 * HID + pc0 * 8;
  const u16* Aad1 = Ag + (size_t)pr1 * HID + pc1 * 8;
  const u16* Bad0 = Bg + (size_t)pr0 * HID + pc0 * 8;
  const u16* Bad1 = Bg + (size_t)pr1 * HID + pc1 * 8;

#define LOADAB(kk, A0, A1, B0, B1)               \
  {                                              \
    int k0_ = (kk) * 64;                         \
    A0 = *(const uint4*)(Aad0 + k0_);            \
    A1 = *(const uint4*)(Aad1 + k0_);            \
    B0 = *(const uint4*)(Bad0 + k0_);            \
    B1 = *(const uint4*)(Bad1 + k0_);            \
  }
#define STOREAB(A0, A1, B0, B1)                  \
  {                                              \
    *(uint4*)&As[w * 512 + lane * 8] = A0;       \
    *(uint4*)&As[(4 + w) * 512 + lane * 8] = A1; \
    *(uint4*)&Bs[w * 512 + lane * 8] = B0;       \
    *(uint4*)&Bs[(4 + w) * 512 + lane * 8] = B1; \
  }
#define COMPUTEC()                                                             \
  {                                                                            \
    int ar = w * 16 + ln;                                                      \
    bf16x8 a0 = *(const bf16x8*)&As[ar * 64 + ((q ^ (ln & 7)) * 8)];           \
    bf16x8 a1 = *(const bf16x8*)&As[ar * 64 + (((q + 4) ^ (ln & 7)) * 8)];     \
    for (int n2 = 0; n2 < 4; ++n2) {                                           \
      int br = n2 * 16 + ln;                                                   \
      bf16x8 b0 = *(const bf16x8*)&Bs[br * 64 + ((q ^ (ln & 7)) * 8)];         \
      bf16x8 b1 = *(const bf16x8*)&Bs[br * 64 + (((q + 4) ^ (ln & 7)) * 8)];   \
      acc[n2] = MFMA16(a0, b0, acc[n2]);                                       \
      acc[n2] = MFMA16(a1, b1, acc[n2]);                                       \
    }                                                                          \
  }

  uint4 aa0, aa1, ba0, ba1, ab0, ab1, bb0, bb1;
  LOADAB(0, aa0, aa1, ba0, ba1);
  for (int kk = 0; kk < 8; kk += 2) {
    if (kk) __syncthreads();
    STOREAB(aa0, aa1, ba0, ba1);
    __syncthreads();
    LOADAB(kk + 1, ab0, ab1, bb0, bb1);
    COMPUTEC();
    __syncthreads();
    STOREAB(ab0, ab1, bb0, bb1);
    __syncthreads();
    if (kk + 2 < 8) LOADAB(kk + 2, aa0, aa1, ba0, ba1);
    COMPUTEC();
  }
#undef LOADAB
#undef STOREAB
#undef COMPUTEC

  float bias[4];
  for (int r = 0; r < 4; ++r) bias[r] = bout[m0 + w * 16 + q * 4 + r];
  for (int n2 = 0; n2 < 4; ++n2) {
    int l = n0 + n2 * 16 + ln;
    for (int r = 0; r < 4; ++r) {
      int o = m0 + w * 16 + q * 4 + r;
      out[((size_t)b * Cn + o) * Ln + l] = acc[n2][r] + bias[r];
    }
  }
}

// ---------------- launch -----------------------------------------------------
extern "C" void kernel_launch(void* const* d_in, const int* in_sizes, int n_in,
                              void* d_out, int out_size, void* d_ws, size_t ws_size,
                              hipStream_t stream) {
  const float* x = (const float*)d_in[0];
  const float* wqkv = (const float*)d_in[1];
  const float* wout = (const float*)d_in[2];
  const float* bout = (const float*)d_in[3];
  float* out = (float*)d_out;
  char* ws = (char*)d_ws;

  u16* wq_b = (u16*)(ws + 0);          // [1536][256] bf16
  u16* wo_b = (u16*)(ws + 786432);     // [256][512]  bf16
  u16* xT   = (u16*)(ws + 1048576);    // [4][2048][256]
  u16* qT   = (u16*)(ws + 5242880);    // [4][8][2048][64]
  u16* kT   = (u16*)(ws + 13631488);   // [4][8][2048][64]
  u16* vv   = (u16*)(ws + 22020096);   // [4][512][2048]
  u16* attT = (u16*)(ws + 30408704);   // [4][2048][512]

  prep_all<<<2560, 256, 0, stream>>>(wqkv, wout, x, wq_b, wo_b, xT);
  qkv_gemm<<<dim3(32, 24, 4), 256, 0, stream>>>(wq_b, xT, qT, kT, vv);
  attention<<<dim3(16, 32), 256, 0, stream>>>(qT, kT, vv, attT);
  out_gemm<<<dim3(32, 4, 4), 256, 0, stream>>>(wo_b, attT, bout, out);
}

// Round 6
// 140.664 us; speedup vs baseline: 1.4079x; 1.0135x over previous
//
#include <hip/hip_runtime.h>

typedef unsigned short u16;
typedef unsigned int u32;
typedef __bf16 bf16x8 __attribute__((ext_vector_type(8)));
typedef float f32x4 __attribute__((ext_vector_type(4)));
typedef float f32x16 __attribute__((ext_vector_type(16)));

#define MFMA16(a, b, c) __builtin_amdgcn_mfma_f32_16x16x32_bf16((a), (b), (c), 0, 0, 0)
#define MFMA32(a, b, c) __builtin_amdgcn_mfma_f32_32x32x16_bf16((a), (b), (c), 0, 0, 0)

// Problem constants
#define Bn 4
#define Cn 256
#define Ln 2048
#define Hn 8
#define Dn 64
#define HID 512
#define SEGELEMS 4194304  // elems per attention-partial segment (4*2048*512)

__device__ __forceinline__ u16 bf16_rne(float f) {
  u32 u = __builtin_bit_cast(u32, f);
  u += 0x7FFFu + ((u >> 16) & 1u);
  return (u16)(u >> 16);
}

__device__ __forceinline__ unsigned pack2(float a, float b) {
  return (unsigned)bf16_rne(a) | ((unsigned)bf16_rne(b) << 16);
}

// cheap bf16 pair pack: round-half-up then byte-perm merge (3 VALU ops)
__device__ __forceinline__ u32 pkperm(float lo, float hi) {
  u32 a = __builtin_bit_cast(u32, lo) + 0x8000u;
  u32 b = __builtin_bit_cast(u32, hi) + 0x8000u;
#if __has_builtin(__builtin_amdgcn_perm)
  return __builtin_amdgcn_perm(b, a, 0x07060302u);
#else
  return (b & 0xFFFF0000u) | (a >> 16);
#endif
}

__device__ __forceinline__ float bf16_up(u16 v) {
  u32 u = ((u32)v) << 16;
  return __builtin_bit_cast(float, u);
}

__device__ __forceinline__ float fast_exp2(float x) {
#if __has_builtin(__builtin_amdgcn_exp2f)
  return __builtin_amdgcn_exp2f(x);
#else
  return exp2f(x);
#endif
}

__device__ __forceinline__ float fast_rcp(float x) {
#if __has_builtin(__builtin_amdgcn_rcpf)
  return __builtin_amdgcn_rcpf(x);
#else
  return 1.0f / x;
#endif
}

// async 16B global -> LDS DMA. HW dest = wave-uniform base + lane*16.
__device__ __forceinline__ void async_load16(const u16* g, u16* l) {
  __builtin_amdgcn_global_load_lds(
      (const __attribute__((address_space(1))) void*)g,
      (__attribute__((address_space(3))) void*)l, 16, 0, 0);
}

// ---------------- prep (merged): weights->bf16 AND x transpose ---------------
__global__ __launch_bounds__(256) void prep_all(const float* __restrict__ wqkv,
                                                const float* __restrict__ wout,
                                                const float* __restrict__ x,
                                                u16* __restrict__ wq,
                                                u16* __restrict__ wo,
                                                u16* __restrict__ xT) {
  const int t = threadIdx.x;
  if (blockIdx.x < 2048) {
    int i = blockIdx.x * 256 + t;
    const float QSCALE = 0.125f * 1.44269504088896340736f;  // scale * log2(e)
    if (i < 3 * HID * Cn) {
      float v = wqkv[i];
      if (i < HID * Cn) v *= QSCALE;  // q rows
      wq[i] = bf16_rne(v);
    } else {
      int j = i - 3 * HID * Cn;
      wo[j] = bf16_rne(wout[j]);
    }
    return;
  }
  __shared__ u16 tile[64][72];
  int v = blockIdx.x - 2048;
  const int lt = v & 31, ct = (v >> 5) & 3, b = v >> 7;
  const float* xp = x + ((size_t)b * Cn + ct * 64) * Ln + lt * 64;
  for (int pass = 0; pass < 4; ++pass) {
    int c = pass * 16 + (t >> 4);
    int l4 = (t & 15) * 4;
    float4 vf = *(const float4*)(xp + (size_t)c * Ln + l4);
    tile[l4 + 0][c] = bf16_rne(vf.x);
    tile[l4 + 1][c] = bf16_rne(vf.y);
    tile[l4 + 2][c] = bf16_rne(vf.z);
    tile[l4 + 3][c] = bf16_rne(vf.w);
  }
  __syncthreads();
  u16* op = xT + ((size_t)b * Ln + lt * 64) * Cn + ct * 64;
  for (int pass = 0; pass < 2; ++pass) {
    int id = pass * 256 + t;
    int l = id >> 3, c8 = (id & 7) * 8;
    *(uint4*)(op + (size_t)l * Cn + c8) = *(const uint4*)&tile[l][c8];
  }
}

// ---------------- QKV GEMM (fused Q/K/V per block): one B staging, 3 A tiles -
__global__ __launch_bounds__(256, 4) void qkv_gemm(const u16* __restrict__ wq,
                                                   const u16* __restrict__ xT,
                                                   u16* __restrict__ qT,
                                                   u16* __restrict__ kT,
                                                   u16* __restrict__ vv) {
  __shared__ u16 Bs[4096];
  __shared__ u16 Aq[4096];
  __shared__ u16 Ak[4096];
  __shared__ u16 Av[4096];
  const int t = threadIdx.x;
  const int nt = blockIdx.x, head = blockIdx.y, b = blockIdx.z;
  const int n0 = nt * 64, m0 = head * 64;
  const int w = t >> 6, lane = t & 63, q = lane >> 4, ln = lane & 15;

  const u16* Bg = xT + ((size_t)b * Ln + n0) * Cn;
  const u16* AgQ = wq + (size_t)m0 * Cn;
  const u16* AgK = wq + (size_t)(512 + m0) * Cn;
  const u16* AgV = wq + (size_t)(1024 + m0) * Cn;

  f32x4 zf = {0.f, 0.f, 0.f, 0.f};
  f32x4 accQ[4], accK[4], accV[4];
  for (int i = 0; i < 4; ++i) { accQ[i] = zf; accK[i] = zf; accV[i] = zf; }

  const int pr0 = w * 8 + (lane >> 3), pr1 = (4 + w) * 8 + (lane >> 3);
  const int pc0 = (lane & 7) ^ (pr0 & 7), pc1 = (lane & 7) ^ (pr1 & 7);

  for (int kk = 0; kk < 4; ++kk) {
    int k0 = kk * 64;
    async_load16(Bg + (size_t)pr0 * Cn + k0 + pc0 * 8, &Bs[w * 512]);
    async_load16(Bg + (size_t)pr1 * Cn + k0 + pc1 * 8, &Bs[(4 + w) * 512]);
    async_load16(AgQ + (size_t)pr0 * Cn + k0 + pc0 * 8, &Aq[w * 512]);
    async_load16(AgQ + (size_t)pr1 * Cn + k0 + pc1 * 8, &Aq[(4 + w) * 512]);
    async_load16(AgK + (size_t)pr0 * Cn + k0 + pc0 * 8, &Ak[w * 512]);
    async_load16(AgK + (size_t)pr1 * Cn + k0 + pc1 * 8, &Ak[(4 + w) * 512]);
    async_load16(AgV + (size_t)pr0 * Cn + k0 + pc0 * 8, &Av[w * 512]);
    async_load16(AgV + (size_t)pr1 * Cn + k0 + pc1 * 8, &Av[(4 + w) * 512]);
    __syncthreads();
    int ar = w * 16 + ln;
    bf16x8 aq0 = *(const bf16x8*)&Aq[ar * 64 + ((q ^ (ln & 7)) * 8)];
    bf16x8 aq1 = *(const bf16x8*)&Aq[ar * 64 + (((q + 4) ^ (ln & 7)) * 8)];
    bf16x8 ak0 = *(const bf16x8*)&Ak[ar * 64 + ((q ^ (ln & 7)) * 8)];
    bf16x8 ak1 = *(const bf16x8*)&Ak[ar * 64 + (((q + 4) ^ (ln & 7)) * 8)];
    bf16x8 av0 = *(const bf16x8*)&Av[ar * 64 + ((q ^ (ln & 7)) * 8)];
    bf16x8 av1 = *(const bf16x8*)&Av[ar * 64 + (((q + 4) ^ (ln & 7)) * 8)];
    for (int n2 = 0; n2 < 4; ++n2) {
      int br = n2 * 16 + ln;
      bf16x8 b0 = *(const bf16x8*)&Bs[br * 64 + ((q ^ (ln & 7)) * 8)];
      bf16x8 b1 = *(const bf16x8*)&Bs[br * 64 + (((q + 4) ^ (ln & 7)) * 8)];
      accQ[n2] = MFMA16(aq0, b0, accQ[n2]);
      accQ[n2] = MFMA16(aq1, b1, accQ[n2]);
      accK[n2] = MFMA16(ak0, b0, accK[n2]);
      accK[n2] = MFMA16(ak1, b1, accK[n2]);
      accV[n2] = MFMA16(av0, b0, accV[n2]);
      accV[n2] = MFMA16(av1, b1, accV[n2]);
    }
    __syncthreads();
  }

  // Epilogues via LDS repack in Bs. Q,K -> transposed [b][h][l][64]; V natural.
  int od0 = w * 16 + q * 4;
  int cw = od0 >> 3, lo = od0 & 7;
  // ---- Q ----
  for (int n2 = 0; n2 < 4; ++n2) {
    int l = n2 * 16 + ln;
    uint2 pk;
    pk.x = pack2(accQ[n2][0], accQ[n2][1]);
    pk.y = pack2(accQ[n2][2], accQ[n2][3]);
    *(uint2*)&Bs[l * 64 + ((cw ^ (l & 7)) * 8) + lo] = pk;
  }
  __syncthreads();
  {
    u16* dst = qT + (((size_t)b * Hn + head) * Ln + n0) * Dn;
    for (int pass = 0; pass < 2; ++pass) {
      int id = pass * 256 + t;
      int l = id >> 3, c = id & 7;
      *(uint4*)(dst + (size_t)l * Dn + c * 8) =
          *(const uint4*)&Bs[l * 64 + ((c ^ (l & 7)) * 8)];
    }
  }
  __syncthreads();
  // ---- K ----
  for (int n2 = 0; n2 < 4; ++n2) {
    int l = n2 * 16 + ln;
    uint2 pk;
    pk.x = pack2(accK[n2][0], accK[n2][1]);
    pk.y = pack2(accK[n2][2], accK[n2][3]);
    *(uint2*)&Bs[l * 64 + ((cw ^ (l & 7)) * 8) + lo] = pk;
  }
  __syncthreads();
  {
    u16* dst = kT + (((size_t)b * Hn + head) * Ln + n0) * Dn;
    for (int pass = 0; pass < 2; ++pass) {
      int id = pass * 256 + t;
      int l = id >> 3, c = id & 7;
      *(uint4*)(dst + (size_t)l * Dn + c * 8) =
          *(const uint4*)&Bs[l * 64 + ((c ^ (l & 7)) * 8)];
    }
  }
  __syncthreads();
  // ---- V ----
  for (int n2 = 0; n2 < 4; ++n2) {
    int l = n2 * 16 + ln;
    int cl = l >> 3, lov = l & 7;
    for (int r = 0; r < 4; ++r) {
      int od = w * 16 + q * 4 + r;
      Bs[od * 64 + ((cl ^ (od & 7)) * 8) + lov] = bf16_rne(accV[n2][r]);
    }
  }
  __syncthreads();
  {
    u16* dst = vv + ((size_t)b * HID + head * 64) * Ln + n0;
    for (int pass = 0; pass < 2; ++pass) {
      int id = pass * 256 + t;
      int od = id >> 3, c = id & 7;
      *(uint4*)(dst + (size_t)od * Ln + c * 8) =
          *(const uint4*)&Bs[od * 64 + ((c ^ (od & 7)) * 8)];
    }
  }
}

// ---------------- Flash attention v6: split-K (2 segs), 4 blocks/CU ----------
// exp2 softmax has no max-shift -> O,l are associative sums; each seg block
// handles 1024 keys, writes unnormalized bf16 O-partial + fp32 l-partial.
__global__ __launch_bounds__(256, 4) void attention(const u16* __restrict__ qT,
                                                    const u16* __restrict__ kT,
                                                    const u16* __restrict__ vv,
                                                    u16* __restrict__ pO,
                                                    float* __restrict__ lP) {
  __shared__ u16 Kt[4096];  // [64 j][64 d], chunk c at c^(j&7)
  __shared__ u16 Vt[4096];  // [64 d][64 j], chunk c at c^(d&7)
  __shared__ u16 Ps[8192];  // 4 waves x [32 i][64 j] swizzled
  const int t = threadIdx.x;
  const int qb = blockIdx.x, bh = blockIdx.y, seg = blockIdx.z;
  const int b = bh >> 3, hh = bh & 7;
  const int w = t >> 6, lane = t & 63;
  const int li = lane & 31, h = lane >> 5;
  const int i0 = qb * 128 + w * 32;

  bf16x8 qf0, qf1, qf2, qf3;
  {
    const u16* qrow = qT + (((size_t)bh) * Ln + i0 + li) * Dn + h * 8;
    qf0 = *(const bf16x8*)(qrow + 0);
    qf1 = *(const bf16x8*)(qrow + 16);
    qf2 = *(const bf16x8*)(qrow + 32);
    qf3 = *(const bf16x8*)(qrow + 48);
  }

  const u16* ksrc0 = kT + ((size_t)bh) * Ln * Dn;
  const u16* vsrc0 = vv + ((size_t)b * HID + hh * Dn) * Ln;

  f32x16 z16;  // persistent zero C-operand (no per-iter re-init movs)
#pragma unroll
  for (int r = 0; r < 16; ++r) z16[r] = 0.f;
  f32x16 o0 = z16, o1 = z16;
  float lp = 0.f;
  u16* pw = Ps + w * 2048;

  const int pr0 = w * 8 + (lane >> 3), pr1 = (4 + w) * 8 + (lane >> 3);
  const int pc0 = (lane & 7) ^ (pr0 & 7), pc1 = (lane & 7) ^ (pr1 & 7);
  const u16* kadr0 = ksrc0 + ((size_t)seg * 1024 + pr0) * Dn + pc0 * 8;
  const u16* kadr1 = ksrc0 + ((size_t)seg * 1024 + pr1) * Dn + pc1 * 8;
  const u16* vadr0 = vsrc0 + (size_t)pr0 * Ln + seg * 1024 + pc0 * 8;
  const u16* vadr1 = vsrc0 + (size_t)pr1 * Ln + seg * 1024 + pc1 * 8;

  const int sw = (li & 7);

  for (int jt = 0; jt < 16; ++jt) {
    int j0 = jt * 64;
    async_load16(kadr0 + (size_t)j0 * Dn, &Kt[w * 512]);
    async_load16(kadr1 + (size_t)j0 * Dn, &Kt[(4 + w) * 512]);
    async_load16(vadr0 + j0, &Vt[w * 512]);
    async_load16(vadr1 + j0, &Vt[(4 + w) * 512]);
    __syncthreads();  // drains DMA (vmcnt) before compute

    // S^T = K·Q^T via MFMA32: D col i = li, rows j (reg pattern)
    f32x16 sv0, sv1;
    {
      bf16x8 k0 = *(const bf16x8*)&Kt[li * 64 + (((0 + h) ^ sw) * 8)];
      bf16x8 k1 = *(const bf16x8*)&Kt[(32 + li) * 64 + (((0 + h) ^ sw) * 8)];
      sv0 = MFMA32(k0, qf0, z16);
      sv1 = MFMA32(k1, qf0, z16);
    }
    {
      bf16x8 k0 = *(const bf16x8*)&Kt[li * 64 + (((2 + h) ^ sw) * 8)];
      bf16x8 k1 = *(const bf16x8*)&Kt[(32 + li) * 64 + (((2 + h) ^ sw) * 8)];
      sv0 = MFMA32(k0, qf1, sv0);
      sv1 = MFMA32(k1, qf1, sv1);
    }
    {
      bf16x8 k0 = *(const bf16x8*)&Kt[li * 64 + (((4 + h) ^ sw) * 8)];
      bf16x8 k1 = *(const bf16x8*)&Kt[(32 + li) * 64 + (((4 + h) ^ sw) * 8)];
      sv0 = MFMA32(k0, qf2, sv0);
      sv1 = MFMA32(k1, qf2, sv1);
    }
    {
      bf16x8 k0 = *(const bf16x8*)&Kt[li * 64 + (((6 + h) ^ sw) * 8)];
      bf16x8 k1 = *(const bf16x8*)&Kt[(32 + li) * 64 + (((6 + h) ^ sw) * 8)];
      sv0 = MFMA32(k0, qf3, sv0);
      sv1 = MFMA32(k1, qf3, sv1);
    }

    // P = exp2(S), pack via perm, accumulate row-sum lp (column i=li)
#pragma unroll
    for (int js = 0; js < 2; ++js) {
#pragma unroll
      for (int g = 0; g < 4; ++g) {
        float e0 = fast_exp2(js ? sv1[4 * g + 0] : sv0[4 * g + 0]);
        float e1 = fast_exp2(js ? sv1[4 * g + 1] : sv0[4 * g + 1]);
        float e2 = fast_exp2(js ? sv1[4 * g + 2] : sv0[4 * g + 2]);
        float e3 = fast_exp2(js ? sv1[4 * g + 3] : sv0[4 * g + 3]);
        lp += (e0 + e1) + (e2 + e3);
        uint2 pk;
        pk.x = pkperm(e0, e1);
        pk.y = pkperm(e2, e3);
        int cjj = js * 4 + g;
        *(uint2*)&pw[li * 64 + ((cjj ^ sw) * 8) + 4 * h] = pk;
      }
    }

    // O += P·V^T (A = P row i=li, B = V rows d)
    bf16x8 pf0 = *(const bf16x8*)&pw[li * 64 + (((0 + h) ^ sw) * 8)];
    bf16x8 pf1 = *(const bf16x8*)&pw[li * 64 + (((2 + h) ^ sw) * 8)];
    bf16x8 pf2 = *(const bf16x8*)&pw[li * 64 + (((4 + h) ^ sw) * 8)];
    bf16x8 pf3 = *(const bf16x8*)&pw[li * 64 + (((6 + h) ^ sw) * 8)];
#pragma unroll
    for (int jc = 0; jc < 4; ++jc) {
      int ch = 2 * jc + h;
      bf16x8 pf = (jc == 0) ? pf0 : (jc == 1) ? pf1 : (jc == 2) ? pf2 : pf3;
      bf16x8 vf0 = *(const bf16x8*)&Vt[li * 64 + ((ch ^ sw) * 8)];
      bf16x8 vf1 = *(const bf16x8*)&Vt[(32 + li) * 64 + ((ch ^ sw) * 8)];
      o0 = MFMA32(pf, vf0, o0);
      o1 = MFMA32(pf, vf1, o1);
    }
    __syncthreads();  // compute done before next iter's DMA lands
  }

  // l partial: lane li's lp covers its h-half of j; sum with partner.
  float lsum = lp + __shfl_xor(lp, 32);
  if (h == 0)
    lP[(((size_t)seg * Bn + b) * Hn + hh) * Ln + i0 + li] = lsum;
  // O partial, unnormalized bf16, att-layout [b][i][h*64+d]
  u16* po = pO + (size_t)seg * SEGELEMS;
#pragma unroll
  for (int r = 0; r < 16; ++r) {
    int ir = (r & 3) + 8 * (r >> 2) + 4 * h;
    size_t base = ((size_t)b * Ln + i0 + ir) * HID + hh * Dn + li;
    po[base] = bf16_rne(o0[r]);
    po[base + 32] = bf16_rne(o1[r]);
  }
}

// ---------------- combine: attT = (O0+O1) / (l0+l1) --------------------------
__global__ __launch_bounds__(256) void combine(const u16* __restrict__ pO,
                                               const float* __restrict__ lP,
                                               u16* __restrict__ attT) {
  int idx8 = (blockIdx.x * 256 + threadIdx.x) * 8;
  int i_lin = idx8 >> 9;           // b*2048 + i
  int h = (idx8 & 511) >> 6;
  int b = i_lin >> 11, i = i_lin & 2047;
  float l = lP[(b * 8 + h) * 2048 + i] + lP[(32 + b * 8 + h) * 2048 + i];
  float s = fast_rcp(l);
  uint4 u0 = *(const uint4*)(pO + idx8);
  uint4 u1 = *(const uint4*)(pO + SEGELEMS + idx8);
  u32 a[4] = {u0.x, u0.y, u0.z, u0.w};
  u32 c[4] = {u1.x, u1.y, u1.z, u1.w};
  uint4 r;
  u32 rw[4];
#pragma unroll
  for (int k = 0; k < 4; ++k) {
    float flo = (bf16_up((u16)(a[k] & 0xFFFF)) + bf16_up((u16)(c[k] & 0xFFFF))) * s;
    float fhi = (bf16_up((u16)(a[k] >> 16)) + bf16_up((u16)(c[k] >> 16))) * s;
    rw[k] = pack2(flo, fhi);
  }
  r.x = rw[0]; r.y = rw[1]; r.z = rw[2]; r.w = rw[3];
  *(uint4*)(attT + idx8) = r;
}

// ---------------- out GEMM: y = wo[256x512] @ att[b][512x2048] + b_out -------
// 64x32 tiles (1024 blocks = 4/CU), reg-prefetch pipeline.
__global__ __launch_bounds__(256, 4) void out_gemm(const u16* __restrict__ wo,
                                                   const u16* __restrict__ attT,
                                                   const float* __restrict__ bout,
                                                   float* __restrict__ out) {
  __shared__ u16 As[4096];  // [64 o][64 k]
  __shared__ u16 Bs[2048];  // [32 l][64 k]
  const int t = threadIdx.x;
  const int nt = blockIdx.x, mt = blockIdx.y, b = blockIdx.z;
  const int m0 = mt * 64, n0 = nt * 32;
  const int w = t >> 6, lane = t & 63, q = lane >> 4, ln = lane & 15;

  const u16* Ag = wo + (size_t)m0 * HID;
  const u16* Bg = attT + ((size_t)b * Ln + n0) * HID;

  f32x4 zf = {0.f, 0.f, 0.f, 0.f};
  f32x4 acc[2];
  acc[0] = zf; acc[1] = zf;

  const int pr0 = w * 8 + (lane >> 3), pr1 = (4 + w) * 8 + (lane >> 3);
  const int pc0 = (lane & 7) ^ (pr0 & 7), pc1 = (lane & 7) ^ (pr1 & 7);
  const u16* Aad0 = Ag + (size_t)pr0 * HID + pc0 * 8;
  const u16* Aad1 = Ag + (size_t)pr1 * HID + pc1 * 8;
  const u16* Bad0 = Bg + (size_t)pr0 * HID + pc0 * 8;  // pr0 in 0..31 for B

#define LOADAB(kk, A0, A1, B0)                   \
  {                                              \
    int k0_ = (kk) * 64;                         \
    A0 = *(const uint4*)(Aad0 + k0_);            \
    A1 = *(const uint4*)(Aad1 + k0_);            \
    B0 = *(const uint4*)(Bad0 + k0_);            \
  }
#define STOREAB(A0, A1, B0)                      \
  {                                              \
    *(uint4*)&As[w * 512 + lane * 8] = A0;       \
    *(uint4*)&As[(4 + w) * 512 + lane * 8] = A1; \
    *(uint4*)&Bs[w * 512 + lane * 8] = B0;       \
  }
#define COMPUTEC()                                                             \
  {                                                                            \
    int ar = w * 16 + ln;                                                      \
    bf16x8 a0 = *(const bf16x8*)&As[ar * 64 + ((q ^ (ln & 7)) * 8)];           \
    bf16x8 a1 = *(const bf16x8*)&As[ar * 64 + (((q + 4) ^ (ln & 7)) * 8)];     \
    for (int n2 = 0; n2 < 2; ++n2) {                                           \
      int br = n2 * 16 + ln;                                                   \
      bf16x8 b0 = *(const bf16x8*)&Bs[br * 64 + ((q ^ (ln & 7)) * 8)];         \
      bf16x8 b1 = *(const bf16x8*)&Bs[br * 64 + (((q + 4) ^ (ln & 7)) * 8)];   \
      acc[n2] = MFMA16(a0, b0, acc[n2]);                                       \
      acc[n2] = MFMA16(a1, b1, acc[n2]);                                       \
    }                                                                          \
  }

  uint4 aa0, aa1, ba0, ab0, ab1, bb0;
  LOADAB(0, aa0, aa1, ba0);
  for (int kk = 0; kk < 8; kk += 2) {
    if (kk) __syncthreads();
    STOREAB(aa0, aa1, ba0);
    __syncthreads();
    LOADAB(kk + 1, ab0, ab1, bb0);
    COMPUTEC();
    __syncthreads();
    STOREAB(ab0, ab1, bb0);
    __syncthreads();
    if (kk + 2 < 8) LOADAB(kk + 2, aa0, aa1, ba0);
    COMPUTEC();
  }
#undef LOADAB
#undef STOREAB
#undef COMPUTEC

  float bias[4];
  for (int r = 0; r < 4; ++r) bias[r] = bout[m0 + w * 16 + q * 4 + r];
  for (int n2 = 0; n2 < 2; ++n2) {
    int l = n0 + n2 * 16 + ln;
    for (int r = 0; r < 4; ++r) {
      int o = m0 + w * 16 + q * 4 + r;
      out[((size_t)b * Cn + o) * Ln + l] = acc[n2][r] + bias[r];
    }
  }
}

// ---------------- launch -----------------------------------------------------
extern "C" void kernel_launch(void* const* d_in, const int* in_sizes, int n_in,
                              void* d_out, int out_size, void* d_ws, size_t ws_size,
                              hipStream_t stream) {
  const float* x = (const float*)d_in[0];
  const float* wqkv = (const float*)d_in[1];
  const float* wout = (const float*)d_in[2];
  const float* bout = (const float*)d_in[3];
  float* out = (float*)d_out;
  char* ws = (char*)d_ws;

  // workspace layout (bytes); X region aliases xT (qkv phase) then pO
  // (attention phase); attT aliases qT (dead after attention). ~43.5 MB total.
  u16* wq_b  = (u16*)(ws + 0);          // [1536][256] bf16          (786432)
  u16* wo_b  = (u16*)(ws + 786432);     // [256][512]  bf16          (262144)
  float* lP  = (float*)(ws + 1048576);  // [2][4][8][2048] f32       (524288)
  u16* qT    = (u16*)(ws + 1572864);    // [4][8][2048][64]          (8 MB)
  u16* kT    = (u16*)(ws + 9961472);    // [4][8][2048][64]          (8 MB)
  u16* vv    = (u16*)(ws + 18350080);   // [4][512][2048]            (8 MB)
  u16* xT    = (u16*)(ws + 26738688);   // [4][2048][256]            (4 MB)
  u16* pO    = (u16*)(ws + 26738688);   // [2][4][2048][512]         (16 MB)
  u16* attT  = qT;                      // reuse qT region after attention

  prep_all<<<2560, 256, 0, stream>>>(wqkv, wout, x, wq_b, wo_b, xT);
  qkv_gemm<<<dim3(32, 8, 4), 256, 0, stream>>>(wq_b, xT, qT, kT, vv);
  attention<<<dim3(16, 32, 2), 256, 0, stream>>>(qT, kT, vv, pO, lP);
  combine<<<2048, 256, 0, stream>>>(pO, lP, attT);
  out_gemm<<<dim3(64, 4, 4), 256, 0, stream>>>(wo_b, attT, bout, out);
}

// Round 7
// 136.307 us; speedup vs baseline: 1.4529x; 1.0320x over previous
//
#include <hip/hip_runtime.h>

typedef unsigned short u16;
typedef unsigned int u32;
typedef __bf16 bf16x8 __attribute__((ext_vector_type(8)));
typedef float f32x4 __attribute__((ext_vector_type(4)));
typedef float f32x8 __attribute__((ext_vector_type(8)));
typedef float f32x16 __attribute__((ext_vector_type(16)));

#define MFMA16(a, b, c) __builtin_amdgcn_mfma_f32_16x16x32_bf16((a), (b), (c), 0, 0, 0)
#define MFMA32(a, b, c) __builtin_amdgcn_mfma_f32_32x32x16_bf16((a), (b), (c), 0, 0, 0)

// Problem constants
#define Bn 4
#define Cn 256
#define Ln 2048
#define Hn 8
#define Dn 64
#define HID 512
#define SEGELEMS 4194304  // elems per attention-partial segment (4*2048*512)

__device__ __forceinline__ u16 bf16_rne(float f) {
  u32 u = __builtin_bit_cast(u32, f);
  u += 0x7FFFu + ((u >> 16) & 1u);
  return (u16)(u >> 16);
}

__device__ __forceinline__ unsigned pack2(float a, float b) {
  return (unsigned)bf16_rne(a) | ((unsigned)bf16_rne(b) << 16);
}

__device__ __forceinline__ float bf16_up(u16 v) {
  u32 u = ((u32)v) << 16;
  return __builtin_bit_cast(float, u);
}

__device__ __forceinline__ float fast_exp2(float x) {
#if __has_builtin(__builtin_amdgcn_exp2f)
  return __builtin_amdgcn_exp2f(x);
#else
  return exp2f(x);
#endif
}

__device__ __forceinline__ float fast_rcp(float x) {
#if __has_builtin(__builtin_amdgcn_rcpf)
  return __builtin_amdgcn_rcpf(x);
#else
  return 1.0f / x;
#endif
}

// async 16B global -> LDS DMA. HW dest = wave-uniform base + lane*16.
__device__ __forceinline__ void async_load16(const u16* g, u16* l) {
  __builtin_amdgcn_global_load_lds(
      (const __attribute__((address_space(1))) void*)g,
      (__attribute__((address_space(3))) void*)l, 16, 0, 0);
}

// ---------------- prep (merged): weights->bf16 AND x transpose ---------------
__global__ __launch_bounds__(256) void prep_all(const float* __restrict__ wqkv,
                                                const float* __restrict__ wout,
                                                const float* __restrict__ x,
                                                u16* __restrict__ wq,
                                                u16* __restrict__ wo,
                                                u16* __restrict__ xT) {
  const int t = threadIdx.x;
  if (blockIdx.x < 2048) {
    int i = blockIdx.x * 256 + t;
    const float QSCALE = 0.125f * 1.44269504088896340736f;  // scale * log2(e)
    if (i < 3 * HID * Cn) {
      float v = wqkv[i];
      if (i < HID * Cn) v *= QSCALE;  // q rows
      wq[i] = bf16_rne(v);
    } else {
      int j = i - 3 * HID * Cn;
      wo[j] = bf16_rne(wout[j]);
    }
    return;
  }
  __shared__ u16 tile[64][72];
  int v = blockIdx.x - 2048;
  const int lt = v & 31, ct = (v >> 5) & 3, b = v >> 7;
  const float* xp = x + ((size_t)b * Cn + ct * 64) * Ln + lt * 64;
  for (int pass = 0; pass < 4; ++pass) {
    int c = pass * 16 + (t >> 4);
    int l4 = (t & 15) * 4;
    float4 vf = *(const float4*)(xp + (size_t)c * Ln + l4);
    tile[l4 + 0][c] = bf16_rne(vf.x);
    tile[l4 + 1][c] = bf16_rne(vf.y);
    tile[l4 + 2][c] = bf16_rne(vf.z);
    tile[l4 + 3][c] = bf16_rne(vf.w);
  }
  __syncthreads();
  u16* op = xT + ((size_t)b * Ln + lt * 64) * Cn + ct * 64;
  for (int pass = 0; pass < 2; ++pass) {
    int id = pass * 256 + t;
    int l = id >> 3, c8 = (id & 7) * 8;
    *(uint4*)(op + (size_t)l * Cn + c8) = *(const uint4*)&tile[l][c8];
  }
}

// ---------------- QKV GEMM (fused Q/K/V per block): one B staging, 3 A tiles -
// V epilogue permutes l-columns (swap bits 2<->3 within each 16) so that the
// attention PV MFMA's k-order matches the S^T C/D lane-native j-order.
__global__ __launch_bounds__(256, 4) void qkv_gemm(const u16* __restrict__ wq,
                                                   const u16* __restrict__ xT,
                                                   u16* __restrict__ qT,
                                                   u16* __restrict__ kT,
                                                   u16* __restrict__ vv) {
  __shared__ u16 Bs[4096];
  __shared__ u16 Aq[4096];
  __shared__ u16 Ak[4096];
  __shared__ u16 Av[4096];
  const int t = threadIdx.x;
  const int nt = blockIdx.x, head = blockIdx.y, b = blockIdx.z;
  const int n0 = nt * 64, m0 = head * 64;
  const int w = t >> 6, lane = t & 63, q = lane >> 4, ln = lane & 15;

  const u16* Bg = xT + ((size_t)b * Ln + n0) * Cn;
  const u16* AgQ = wq + (size_t)m0 * Cn;
  const u16* AgK = wq + (size_t)(512 + m0) * Cn;
  const u16* AgV = wq + (size_t)(1024 + m0) * Cn;

  f32x4 zf = {0.f, 0.f, 0.f, 0.f};
  f32x4 accQ[4], accK[4], accV[4];
  for (int i = 0; i < 4; ++i) { accQ[i] = zf; accK[i] = zf; accV[i] = zf; }

  const int pr0 = w * 8 + (lane >> 3), pr1 = (4 + w) * 8 + (lane >> 3);
  const int pc0 = (lane & 7) ^ (pr0 & 7), pc1 = (lane & 7) ^ (pr1 & 7);

  for (int kk = 0; kk < 4; ++kk) {
    int k0 = kk * 64;
    async_load16(Bg + (size_t)pr0 * Cn + k0 + pc0 * 8, &Bs[w * 512]);
    async_load16(Bg + (size_t)pr1 * Cn + k0 + pc1 * 8, &Bs[(4 + w) * 512]);
    async_load16(AgQ + (size_t)pr0 * Cn + k0 + pc0 * 8, &Aq[w * 512]);
    async_load16(AgQ + (size_t)pr1 * Cn + k0 + pc1 * 8, &Aq[(4 + w) * 512]);
    async_load16(AgK + (size_t)pr0 * Cn + k0 + pc0 * 8, &Ak[w * 512]);
    async_load16(AgK + (size_t)pr1 * Cn + k0 + pc1 * 8, &Ak[(4 + w) * 512]);
    async_load16(AgV + (size_t)pr0 * Cn + k0 + pc0 * 8, &Av[w * 512]);
    async_load16(AgV + (size_t)pr1 * Cn + k0 + pc1 * 8, &Av[(4 + w) * 512]);
    __syncthreads();
    int ar = w * 16 + ln;
    bf16x8 aq0 = *(const bf16x8*)&Aq[ar * 64 + ((q ^ (ln & 7)) * 8)];
    bf16x8 aq1 = *(const bf16x8*)&Aq[ar * 64 + (((q + 4) ^ (ln & 7)) * 8)];
    bf16x8 ak0 = *(const bf16x8*)&Ak[ar * 64 + ((q ^ (ln & 7)) * 8)];
    bf16x8 ak1 = *(const bf16x8*)&Ak[ar * 64 + (((q + 4) ^ (ln & 7)) * 8)];
    bf16x8 av0 = *(const bf16x8*)&Av[ar * 64 + ((q ^ (ln & 7)) * 8)];
    bf16x8 av1 = *(const bf16x8*)&Av[ar * 64 + (((q + 4) ^ (ln & 7)) * 8)];
    for (int n2 = 0; n2 < 4; ++n2) {
      int br = n2 * 16 + ln;
      bf16x8 b0 = *(const bf16x8*)&Bs[br * 64 + ((q ^ (ln & 7)) * 8)];
      bf16x8 b1 = *(const bf16x8*)&Bs[br * 64 + (((q + 4) ^ (ln & 7)) * 8)];
      accQ[n2] = MFMA16(aq0, b0, accQ[n2]);
      accQ[n2] = MFMA16(aq1, b1, accQ[n2]);
      accK[n2] = MFMA16(ak0, b0, accK[n2]);
      accK[n2] = MFMA16(ak1, b1, accK[n2]);
      accV[n2] = MFMA16(av0, b0, accV[n2]);
      accV[n2] = MFMA16(av1, b1, accV[n2]);
    }
    __syncthreads();
  }

  // Epilogues via LDS repack in Bs. Q,K -> transposed [b][h][l][64]; V natural
  // (but with l-columns bit-2/3-swapped within each 16).
  int od0 = w * 16 + q * 4;
  int cw = od0 >> 3, lo = od0 & 7;
  // ---- Q ----
  for (int n2 = 0; n2 < 4; ++n2) {
    int l = n2 * 16 + ln;
    uint2 pk;
    pk.x = pack2(accQ[n2][0], accQ[n2][1]);
    pk.y = pack2(accQ[n2][2], accQ[n2][3]);
    *(uint2*)&Bs[l * 64 + ((cw ^ (l & 7)) * 8) + lo] = pk;
  }
  __syncthreads();
  {
    u16* dst = qT + (((size_t)b * Hn + head) * Ln + n0) * Dn;
    for (int pass = 0; pass < 2; ++pass) {
      int id = pass * 256 + t;
      int l = id >> 3, c = id & 7;
      *(uint4*)(dst + (size_t)l * Dn + c * 8) =
          *(const uint4*)&Bs[l * 64 + ((c ^ (l & 7)) * 8)];
    }
  }
  __syncthreads();
  // ---- K ----
  for (int n2 = 0; n2 < 4; ++n2) {
    int l = n2 * 16 + ln;
    uint2 pk;
    pk.x = pack2(accK[n2][0], accK[n2][1]);
    pk.y = pack2(accK[n2][2], accK[n2][3]);
    *(uint2*)&Bs[l * 64 + ((cw ^ (l & 7)) * 8) + lo] = pk;
  }
  __syncthreads();
  {
    u16* dst = kT + (((size_t)b * Hn + head) * Ln + n0) * Dn;
    for (int pass = 0; pass < 2; ++pass) {
      int id = pass * 256 + t;
      int l = id >> 3, c = id & 7;
      *(uint4*)(dst + (size_t)l * Dn + c * 8) =
          *(const uint4*)&Bs[l * 64 + ((c ^ (l & 7)) * 8)];
    }
  }
  __syncthreads();
  // ---- V (l-permuted: swap bits 2 and 3 of l) ----
  for (int n2 = 0; n2 < 4; ++n2) {
    int l = n2 * 16 + ln;
    int lpm = (l & ~12) | ((l & 4) << 1) | ((l & 8) >> 1);
    int cl = lpm >> 3, lov = lpm & 7;
    for (int r = 0; r < 4; ++r) {
      int od = w * 16 + q * 4 + r;
      Bs[od * 64 + ((cl ^ (od & 7)) * 8) + lov] = bf16_rne(accV[n2][r]);
    }
  }
  __syncthreads();
  {
    u16* dst = vv + ((size_t)b * HID + head * 64) * Ln + n0;
    for (int pass = 0; pass < 2; ++pass) {
      int id = pass * 256 + t;
      int od = id >> 3, c = id & 7;
      *(uint4*)(dst + (size_t)od * Ln + c * 8) =
          *(const uint4*)&Bs[od * 64 + ((c ^ (od & 7)) * 8)];
    }
  }
}

// ---------------- Flash attention v7: P-in-register ---------------------------
// split-K (2 segs), 128 q/block, 32 q/wave, 32x32x16 MFMA.
// S^T C/D holds column i=lane — the exact A-operand distribution PV needs.
// V's j-columns are pre-permuted (qkv epilogue) so A/B k-orders agree:
// pf_jc = cvt(exp2(sv_half[8jc..8jc+7])). No P LDS, no cross-lane ops.
__global__ __launch_bounds__(256, 4) void attention(const u16* __restrict__ qT,
                                                    const u16* __restrict__ kT,
                                                    const u16* __restrict__ vv,
                                                    u16* __restrict__ pO,
                                                    float* __restrict__ lP) {
  __shared__ u16 Kt[4096];  // [64 j][64 d], chunk c at c^(j&7)
  __shared__ u16 Vt[4096];  // [64 d][64 jpos], chunk c at c^(d&7)
  const int t = threadIdx.x;
  const int qb = blockIdx.x, bh = blockIdx.y, seg = blockIdx.z;
  const int b = bh >> 3, hh = bh & 7;
  const int w = t >> 6, lane = t & 63;
  const int li = lane & 31, h = lane >> 5;
  const int i0 = qb * 128 + w * 32;

  bf16x8 qf0, qf1, qf2, qf3;
  {
    const u16* qrow = qT + (((size_t)bh) * Ln + i0 + li) * Dn + h * 8;
    qf0 = *(const bf16x8*)(qrow + 0);
    qf1 = *(const bf16x8*)(qrow + 16);
    qf2 = *(const bf16x8*)(qrow + 32);
    qf3 = *(const bf16x8*)(qrow + 48);
  }

  const u16* ksrc0 = kT + ((size_t)bh) * Ln * Dn;
  const u16* vsrc0 = vv + ((size_t)b * HID + hh * Dn) * Ln;

  f32x16 z16;  // persistent zero C-operand
#pragma unroll
  for (int r = 0; r < 16; ++r) z16[r] = 0.f;
  f32x16 o0 = z16, o1 = z16;
  float lp = 0.f;

  const int pr0 = w * 8 + (lane >> 3), pr1 = (4 + w) * 8 + (lane >> 3);
  const int pc0 = (lane & 7) ^ (pr0 & 7), pc1 = (lane & 7) ^ (pr1 & 7);
  const u16* kadr0 = ksrc0 + ((size_t)seg * 1024 + pr0) * Dn + pc0 * 8;
  const u16* kadr1 = ksrc0 + ((size_t)seg * 1024 + pr1) * Dn + pc1 * 8;
  const u16* vadr0 = vsrc0 + (size_t)pr0 * Ln + seg * 1024 + pc0 * 8;
  const u16* vadr1 = vsrc0 + (size_t)pr1 * Ln + seg * 1024 + pc1 * 8;

  const int sw = (li & 7);

  for (int jt = 0; jt < 16; ++jt) {
    int j0 = jt * 64;
    async_load16(kadr0 + (size_t)j0 * Dn, &Kt[w * 512]);
    async_load16(kadr1 + (size_t)j0 * Dn, &Kt[(4 + w) * 512]);
    async_load16(vadr0 + j0, &Vt[w * 512]);
    async_load16(vadr1 + j0, &Vt[(4 + w) * 512]);
    __syncthreads();  // drains DMA (vmcnt) before compute

    // S^T = K·Q^T via MFMA32: D col i = li, rows j (reg pattern)
    f32x16 sv0, sv1;
    {
      bf16x8 k0 = *(const bf16x8*)&Kt[li * 64 + (((0 + h) ^ sw) * 8)];
      bf16x8 k1 = *(const bf16x8*)&Kt[(32 + li) * 64 + (((0 + h) ^ sw) * 8)];
      sv0 = MFMA32(k0, qf0, z16);
      sv1 = MFMA32(k1, qf0, z16);
    }
    {
      bf16x8 k0 = *(const bf16x8*)&Kt[li * 64 + (((2 + h) ^ sw) * 8)];
      bf16x8 k1 = *(const bf16x8*)&Kt[(32 + li) * 64 + (((2 + h) ^ sw) * 8)];
      sv0 = MFMA32(k0, qf1, sv0);
      sv1 = MFMA32(k1, qf1, sv1);
    }
    {
      bf16x8 k0 = *(const bf16x8*)&Kt[li * 64 + (((4 + h) ^ sw) * 8)];
      bf16x8 k1 = *(const bf16x8*)&Kt[(32 + li) * 64 + (((4 + h) ^ sw) * 8)];
      sv0 = MFMA32(k0, qf2, sv0);
      sv1 = MFMA32(k1, qf2, sv1);
    }
    {
      bf16x8 k0 = *(const bf16x8*)&Kt[li * 64 + (((6 + h) ^ sw) * 8)];
      bf16x8 k1 = *(const bf16x8*)&Kt[(32 + li) * 64 + (((6 + h) ^ sw) * 8)];
      sv0 = MFMA32(k0, qf3, sv0);
      sv1 = MFMA32(k1, qf3, sv1);
    }

    // P = exp2(S) in place; accumulate row-sum lp (this lane's i=li column)
#pragma unroll
    for (int g = 0; g < 16; ++g) {
      sv0[g] = fast_exp2(sv0[g]);
      sv1[g] = fast_exp2(sv1[g]);
      lp += sv0[g] + sv1[g];
    }
    // A-frags directly from registers (j-order matches permuted V)
    f32x8 e0 = __builtin_shufflevector(sv0, sv0, 0, 1, 2, 3, 4, 5, 6, 7);
    f32x8 e1 = __builtin_shufflevector(sv0, sv0, 8, 9, 10, 11, 12, 13, 14, 15);
    f32x8 e2 = __builtin_shufflevector(sv1, sv1, 0, 1, 2, 3, 4, 5, 6, 7);
    f32x8 e3 = __builtin_shufflevector(sv1, sv1, 8, 9, 10, 11, 12, 13, 14, 15);
    bf16x8 pf0 = __builtin_convertvector(e0, bf16x8);
    bf16x8 pf1 = __builtin_convertvector(e1, bf16x8);
    bf16x8 pf2 = __builtin_convertvector(e2, bf16x8);
    bf16x8 pf3 = __builtin_convertvector(e3, bf16x8);

    // O += P·V (A=P in regs, B=V-frag from LDS)
#pragma unroll
    for (int jc = 0; jc < 4; ++jc) {
      int ch = 2 * jc + h;
      bf16x8 pf = (jc == 0) ? pf0 : (jc == 1) ? pf1 : (jc == 2) ? pf2 : pf3;
      bf16x8 vf0 = *(const bf16x8*)&Vt[li * 64 + ((ch ^ sw) * 8)];
      bf16x8 vf1 = *(const bf16x8*)&Vt[(32 + li) * 64 + ((ch ^ sw) * 8)];
      o0 = MFMA32(pf, vf0, o0);
      o1 = MFMA32(pf, vf1, o1);
    }
    __syncthreads();  // compute done before next iter's DMA lands
  }

  // l partial: lane li's lp covers its h-half of j; sum with partner.
  float lsum = lp + __shfl_xor(lp, 32);
  if (h == 0)
    lP[(((size_t)seg * Bn + b) * Hn + hh) * Ln + i0 + li] = lsum;
  // O partial, unnormalized bf16, att-layout [b][i][h*64+d]
  u16* po = pO + (size_t)seg * SEGELEMS;
#pragma unroll
  for (int r = 0; r < 16; ++r) {
    int ir = (r & 3) + 8 * (r >> 2) + 4 * h;
    size_t base = ((size_t)b * Ln + i0 + ir) * HID + hh * Dn + li;
    po[base] = bf16_rne(o0[r]);
    po[base + 32] = bf16_rne(o1[r]);
  }
}

// ---------------- combine: attT = (O0+O1) / (l0+l1) --------------------------
__global__ __launch_bounds__(256) void combine(const u16* __restrict__ pO,
                                               const float* __restrict__ lP,
                                               u16* __restrict__ attT) {
  int idx8 = (blockIdx.x * 256 + threadIdx.x) * 8;
  int i_lin = idx8 >> 9;           // b*2048 + i
  int h = (idx8 & 511) >> 6;
  int b = i_lin >> 11, i = i_lin & 2047;
  float l = lP[(b * 8 + h) * 2048 + i] + lP[(32 + b * 8 + h) * 2048 + i];
  float s = fast_rcp(l);
  uint4 u0 = *(const uint4*)(pO + idx8);
  uint4 u1 = *(const uint4*)(pO + SEGELEMS + idx8);
  u32 a[4] = {u0.x, u0.y, u0.z, u0.w};
  u32 c[4] = {u1.x, u1.y, u1.z, u1.w};
  uint4 r;
  u32 rw[4];
#pragma unroll
  for (int k = 0; k < 4; ++k) {
    float flo = (bf16_up((u16)(a[k] & 0xFFFF)) + bf16_up((u16)(c[k] & 0xFFFF))) * s;
    float fhi = (bf16_up((u16)(a[k] >> 16)) + bf16_up((u16)(c[k] >> 16))) * s;
    rw[k] = pack2(flo, fhi);
  }
  r.x = rw[0]; r.y = rw[1]; r.z = rw[2]; r.w = rw[3];
  *(uint4*)(attT + idx8) = r;
}

// ---------------- out GEMM: y = wo[256x512] @ att[b][512x2048] + b_out -------
// 64x32 tiles (1024 blocks = 4/CU), reg-prefetch pipeline.
__global__ __launch_bounds__(256, 4) void out_gemm(const u16* __restrict__ wo,
                                                   const u16* __restrict__ attT,
                                                   const float* __restrict__ bout,
                                                   float* __restrict__ out) {
  __shared__ u16 As[4096];  // [64 o][64 k]
  __shared__ u16 Bs[2048];  // [32 l][64 k]
  const int t = threadIdx.x;
  const int nt = blockIdx.x, mt = blockIdx.y, b = blockIdx.z;
  const int m0 = mt * 64, n0 = nt * 32;
  const int w = t >> 6, lane = t & 63, q = lane >> 4, ln = lane & 15;

  const u16* Ag = wo + (size_t)m0 * HID;
  const u16* Bg = attT + ((size_t)b * Ln + n0) * HID;

  f32x4 zf = {0.f, 0.f, 0.f, 0.f};
  f32x4 acc[2];
  acc[0] = zf; acc[1] = zf;

  const int pr0 = w * 8 + (lane >> 3), pr1 = (4 + w) * 8 + (lane >> 3);
  const int pc0 = (lane & 7) ^ (pr0 & 7), pc1 = (lane & 7) ^ (pr1 & 7);
  const u16* Aad0 = Ag + (size_t)pr0 * HID + pc0 * 8;
  const u16* Aad1 = Ag + (size_t)pr1 * HID + pc1 * 8;
  const u16* Bad0 = Bg + (size_t)pr0 * HID + pc0 * 8;  // pr0 in 0..31 for B

#define LOADAB(kk, A0, A1, B0)                   \
  {                                              \
    int k0_ = (kk) * 64;                         \
    A0 = *(const uint4*)(Aad0 + k0_);            \
    A1 = *(const uint4*)(Aad1 + k0_);            \
    B0 = *(const uint4*)(Bad0 + k0_);            \
  }
#define STOREAB(A0, A1, B0)                      \
  {                                              \
    *(uint4*)&As[w * 512 + lane * 8] = A0;       \
    *(uint4*)&As[(4 + w) * 512 + lane * 8] = A1; \
    *(uint4*)&Bs[w * 512 + lane * 8] = B0;       \
  }
#define COMPUTEC()                                                             \
  {                                                                            \
    int ar = w * 16 + ln;                                                      \
    bf16x8 a0 = *(const bf16x8*)&As[ar * 64 + ((q ^ (ln & 7)) * 8)];           \
    bf16x8 a1 = *(const bf16x8*)&As[ar * 64 + (((q + 4) ^ (ln & 7)) * 8)];     \
    for (int n2 = 0; n2 < 2; ++n2) {                                           \
      int br = n2 * 16 + ln;                                                   \
      bf16x8 b0 = *(const bf16x8*)&Bs[br * 64 + ((q ^ (ln & 7)) * 8)];         \
      bf16x8 b1 = *(const bf16x8*)&Bs[br * 64 + (((q + 4) ^ (ln & 7)) * 8)];   \
      acc[n2] = MFMA16(a0, b0, acc[n2]);                                       \
      acc[n2] = MFMA16(a1, b1, acc[n2]);                                       \
    }                                                                          \
  }

  uint4 aa0, aa1, ba0, ab0, ab1, bb0;
  LOADAB(0, aa0, aa1, ba0);
  for (int kk = 0; kk < 8; kk += 2) {
    if (kk) __syncthreads();
    STOREAB(aa0, aa1, ba0);
    __syncthreads();
    LOADAB(kk + 1, ab0, ab1, bb0);
    COMPUTEC();
    __syncthreads();
    STOREAB(ab0, ab1, bb0);
    __syncthreads();
    if (kk + 2 < 8) LOADAB(kk + 2, aa0, aa1, ba0);
    COMPUTEC();
  }
#undef LOADAB
#undef STOREAB
#undef COMPUTEC

  float bias[4];
  for (int r = 0; r < 4; ++r) bias[r] = bout[m0 + w * 16 + q * 4 + r];
  for (int n2 = 0; n2 < 2; ++n2) {
    int l = n0 + n2 * 16 + ln;
    for (int r = 0; r < 4; ++r) {
      int o = m0 + w * 16 + q * 4 + r;
      out[((size_t)b * Cn + o) * Ln + l] = acc[n2][r] + bias[r];
    }
  }
}

// ---------------- launch -----------------------------------------------------
extern "C" void kernel_launch(void* const* d_in, const int* in_sizes, int n_in,
                              void* d_out, int out_size, void* d_ws, size_t ws_size,
                              hipStream_t stream) {
  const float* x = (const float*)d_in[0];
  const float* wqkv = (const float*)d_in[1];
  const float* wout = (const float*)d_in[2];
  const float* bout = (const float*)d_in[3];
  float* out = (float*)d_out;
  char* ws = (char*)d_ws;

  u16* wq_b  = (u16*)(ws + 0);          // [1536][256] bf16          (786432)
  u16* wo_b  = (u16*)(ws + 786432);     // [256][512]  bf16          (262144)
  float* lP  = (float*)(ws + 1048576);  // [2][4][8][2048] f32       (524288)
  u16* qT    = (u16*)(ws + 1572864);    // [4][8][2048][64]          (8 MB)
  u16* kT    = (u16*)(ws + 9961472);    // [4][8][2048][64]          (8 MB)
  u16* vv    = (u16*)(ws + 18350080);   // [4][512][2048] (l-permuted) (8 MB)
  u16* xT    = (u16*)(ws + 26738688);   // [4][2048][256]            (4 MB)
  u16* pO    = (u16*)(ws + 26738688);   // [2][4][2048][512]         (16 MB)
  u16* attT  = qT;                      // reuse qT region after attention

  prep_all<<<2560, 256, 0, stream>>>(wqkv, wout, x, wq_b, wo_b, xT);
  qkv_gemm<<<dim3(32, 8, 4), 256, 0, stream>>>(wq_b, xT, qT, kT, vv);
  attention<<<dim3(16, 32, 2), 256, 0, stream>>>(qT, kT, vv, pO, lP);
  combine<<<2048, 256, 0, stream>>>(pO, lP, attT);
  out_gemm<<<dim3(64, 4, 4), 256, 0, stream>>>(wo_b, attT, bout, out);
}